// Round 11
// baseline (428.309 us; speedup 1.0000x reference)
//
#include <hip/hip_runtime.h>
#include <stdint.h>

typedef __bf16 bf16x8 __attribute__((ext_vector_type(8)));
typedef float  f32x4  __attribute__((ext_vector_type(4)));
typedef unsigned short ushort_t;

#define MFMA16(a,b,c) __builtin_amdgcn_mfma_f32_16x16x32_bf16((a),(b),(c),0,0,0)

// async global->LDS, 16B per lane; LDS dest must be wave-uniform base (HW adds lane*16)
#define GLOAD16(gsrc, ldst) \
    __builtin_amdgcn_global_load_lds((const __attribute__((address_space(1))) void*)(gsrc), \
                                     (__attribute__((address_space(3))) void*)(ldst), 16, 0, 0)

// ---------- constants ----------
#define BATCH 256
#define NTOK  256
#define DIM   512
#define NH    8
#define HD    64
#define PD    32
#define LTAB  961

// workspace layout (bytes)
#define POS_OFF   0                         // 961*8*4
#define RPB_OFF   32768                     // 8*256*256*4 = 2 MB
#define WQKV_OFF  (RPB_OFF + 2097152)       // 1536*512*2
#define WPROJ_OFF (WQKV_OFF + 1572864)      // 512*512*2
#define QKV_OFF   (WPROJ_OFF + 524288)      // 3*256*8*256*64*2 = 192 MB
#define AOUT_OFF  (QKV_OFF + 201326592)     // 65536*512*2 = 64 MB
#define XB_OFF    AOUT_OFF                  // xb overlays aout: disjoint lifetimes

__device__ __forceinline__ ushort_t f2bf(float f) {
    unsigned int u = __builtin_bit_cast(unsigned int, f);
    u += 0x7FFFu + ((u >> 16) & 1u);
    return (ushort_t)(u >> 16);
}

// ---------- x fp32 -> bf16 ----------
__global__ __launch_bounds__(256) void convert_x(
    const float* __restrict__ x, ushort_t* __restrict__ xb)
{
    size_t i = ((size_t)blockIdx.x * 256 + threadIdx.x) * 8;
    float4 f0 = *(const float4*)(x + i);
    float4 f1 = *(const float4*)(x + i + 4);
    uint4 o;
    o.x = (unsigned)f2bf(f0.x) | ((unsigned)f2bf(f0.y) << 16);
    o.y = (unsigned)f2bf(f0.z) | ((unsigned)f2bf(f0.w) << 16);
    o.z = (unsigned)f2bf(f1.x) | ((unsigned)f2bf(f1.y) << 16);
    o.w = (unsigned)f2bf(f1.z) | ((unsigned)f2bf(f1.w) << 16);
    *reinterpret_cast<uint4*>(xb + i) = o;
}

// ---------- weight transpose + bf16 convert via LDS ----------
__global__ __launch_bounds__(256) void transpose_w(
    const float* __restrict__ src, ushort_t* __restrict__ dst, int K, int Nn)
{
    __shared__ ushort_t tile[64][65];
    int tiles_n = Nn >> 6;
    int tn = blockIdx.x % tiles_n, tk = blockIdx.x / tiles_n;
    int n0 = tn * 64, k0 = tk * 64;
    int t = threadIdx.x;
#pragma unroll
    for (int i = 0; i < 16; i++) {
        int idx = t + i * 256;
        int kl = idx >> 6, nl = idx & 63;
        tile[nl][kl] = f2bf(src[(size_t)(k0 + kl) * Nn + n0 + nl]);
    }
    __syncthreads();
#pragma unroll
    for (int i = 0; i < 16; i++) {
        int idx = t + i * 256;
        int nl = idx >> 6, kl = idx & 63;
        dst[(size_t)(n0 + nl) * K + k0 + kl] = tile[nl][kl];
    }
}

// ---------- dynamic position bias MLP ----------
__device__ __forceinline__ float ln_relu_t(float h, int j,
                                           const float* __restrict__ g,
                                           const float* __restrict__ bb) {
    float m = h;
    m += __shfl_xor(m, 1); m += __shfl_xor(m, 2); m += __shfl_xor(m, 4);
    m += __shfl_xor(m, 8); m += __shfl_xor(m, 16);
    m *= (1.0f / PD);
    float d = h - m;
    float v = d * d;
    v += __shfl_xor(v, 1); v += __shfl_xor(v, 2); v += __shfl_xor(v, 4);
    v += __shfl_xor(v, 8); v += __shfl_xor(v, 16);
    v *= (1.0f / PD);
    float x = d * rsqrtf(v + 1e-5f) * g[j] + bb[j];
    return x > 0.f ? x : 0.f;
}

__global__ __launch_bounds__(256) void pos_mlp(
    const float* __restrict__ biases,
    const float* __restrict__ p1_w, const float* __restrict__ p1_b,
    const float* __restrict__ g1, const float* __restrict__ b1,
    const float* __restrict__ p2_w, const float* __restrict__ p2_b,
    const float* __restrict__ g2, const float* __restrict__ b2,
    const float* __restrict__ p3_w, const float* __restrict__ p3_b,
    const float* __restrict__ g3, const float* __restrict__ b3,
    const float* __restrict__ p4_w, const float* __restrict__ p4_b,
    float* __restrict__ pos)
{
    __shared__ float hs[8][33];
    int tid = threadIdx.x;
    int rl = tid >> 5, j = tid & 31;
    int r = blockIdx.x * 8 + rl;
    bool ok = r < LTAB;
    float c0 = ok ? biases[r * 2 + 0] : 0.f;
    float c1 = ok ? biases[r * 2 + 1] : 0.f;

    float h = c0 * p1_w[j] + c1 * p1_w[PD + j] + p1_b[j];
    h = ln_relu_t(h, j, g1, b1);

    hs[rl][j] = h;
    __syncthreads();
    float s = p2_b[j];
#pragma unroll
    for (int i = 0; i < PD; i++) s += hs[rl][i] * p2_w[i * PD + j];
    __syncthreads();
    h = ln_relu_t(s, j, g2, b2);

    hs[rl][j] = h;
    __syncthreads();
    s = p3_b[j];
#pragma unroll
    for (int i = 0; i < PD; i++) s += hs[rl][i] * p3_w[i * PD + j];
    __syncthreads();
    h = ln_relu_t(s, j, g3, b3);

    hs[rl][j] = h;
    __syncthreads();
    if (ok && j < NH) {
        float o = p4_b[j];
#pragma unroll
        for (int i = 0; i < PD; i++) o += hs[rl][i] * p4_w[i * NH + j];
        pos[r * NH + j] = o;
    }
}

// ---------- rpb gather ----------
__global__ __launch_bounds__(256) void rpb_gather(
    const float* __restrict__ pos, const int* __restrict__ rel_idx,
    float* __restrict__ rpb)
{
    int i = blockIdx.x * 256 + threadIdx.x;   // < 65536
    int idx = rel_idx[i];
#pragma unroll
    for (int hh = 0; hh < NH; hh++) rpb[(size_t)hh * 65536 + i] = pos[idx * NH + hh];
}

// ---------- QKV GEMM: 256x256 tile, BK=64, 8 waves, dbuf 2-phase (round-8 best) ----------
__global__ __launch_bounds__(512, 1) void qkv_gemm(
    const ushort_t* __restrict__ xb, const ushort_t* __restrict__ wT,
    const float* __restrict__ qkv_b, ushort_t* __restrict__ qkvb)
{
    __shared__ ushort_t As[2][256 * 64];   // 32 KB each buf
    __shared__ ushort_t Bs[2][256 * 64];
    int t = threadIdx.x;
    int bid = blockIdx.x;
    int wgid = (bid & 7) * 192 + (bid >> 3);    // 1536 wgs, 192/XCD
    int mt = wgid / 6, nt = wgid % 6;           // n fastest within XCD chunk
    int m0 = mt * 256, n0 = nt * 256;
    int lane = t & 63, w = t >> 6;              // 8 waves
    int wm = w >> 2, wn = w & 3;                // 2M x 4N wave grid, wave out 128x64
    int lr = lane & 15, lk = lane >> 4;
    int srow8 = lane >> 3;
    int sch = ((lane & 7) ^ srow8) * 8;         // pre-swizzled source chunk
    const ushort_t* Asrc = xb + (size_t)(m0 + srow8) * 512 + sch;
    const ushort_t* Bsrc = wT + (size_t)(n0 + srow8) * 512 + sch;
    int arw = w & 3;
    int ch0 = ((lk) ^ (lr & 7)) * 8;
    int ch1 = ((4 + lk) ^ (lr & 7)) * 8;
    int arow = wm * 128 + lr;
    int brow = wn * 64 + lr;

    f32x4 acc[8][4];
#pragma unroll
    for (int fr = 0; fr < 8; fr++)
#pragma unroll
        for (int fc = 0; fc < 4; fc++) acc[fr][fc] = (f32x4){0.f, 0.f, 0.f, 0.f};

#define QSTAGE(buf, kt) do { \
    if (w < 4) { \
        _Pragma("unroll") \
        for (int i_ = 0; i_ < 8; i_++) { \
            int rb_ = arw * 64 + i_ * 8; \
            GLOAD16(Asrc + (size_t)rb_ * 512 + (kt) * 64, &As[buf][rb_ * 64]); \
        } \
    } else { \
        _Pragma("unroll") \
        for (int i_ = 0; i_ < 8; i_++) { \
            int rb_ = arw * 64 + i_ * 8; \
            GLOAD16(Bsrc + (size_t)rb_ * 512 + (kt) * 64, &Bs[buf][rb_ * 64]); \
        } \
    } } while (0)

    QSTAGE(0, 0);
    asm volatile("s_waitcnt vmcnt(0)" ::: "memory");
    __syncthreads();
    for (int kt = 0; kt < 8; ++kt) {
        int cb = kt & 1;
        if (kt < 7) QSTAGE(cb ^ 1, kt + 1);     // latency hides under compute below
#pragma unroll
        for (int kh = 0; kh < 2; kh++) {
            int ch = kh ? ch1 : ch0;
            bf16x8 a[8], b[4];
#pragma unroll
            for (int fr = 0; fr < 8; fr++)
                a[fr] = *reinterpret_cast<const bf16x8*>(&As[cb][(arow + fr * 16) * 64 + ch]);
#pragma unroll
            for (int fc = 0; fc < 4; fc++)
                b[fc] = *reinterpret_cast<const bf16x8*>(&Bs[cb][(brow + fc * 16) * 64 + ch]);
#pragma unroll
            for (int fr = 0; fr < 8; fr++)
#pragma unroll
                for (int fc = 0; fc < 4; fc++)
                    acc[fr][fc] = MFMA16(a[fr], b[fc], acc[fr][fc]);
        }
        if (kt < 7) {
            asm volatile("s_waitcnt vmcnt(0)" ::: "memory");
            __syncthreads();
        }
    }
#undef QSTAGE

    // epilogue: s = q/k/v uniform per block; bg uniform (m0 mult of 256)
    int s = n0 >> 9;
    int bg = m0 >> 8;
    if (s < 2) {
        float sc = (s == 0) ? 0.125f : 1.0f;
#pragma unroll
        for (int fc = 0; fc < 4; fc++) {
            int n = n0 + wn * 64 + fc * 16 + lr;
            float bias = qkv_b[n];
            int hh = (n >> 6) & 7, d = n & 63;
            ushort_t* dst = qkvb + ((((size_t)s * 256 + bg) * 8 + hh) * 256) * 64 + d;
#pragma unroll
            for (int fr = 0; fr < 8; fr++)
#pragma unroll
                for (int r = 0; r < 4; r++) {
                    int tok = wm * 128 + fr * 16 + lk * 4 + r;
                    dst[(size_t)tok * 64] = f2bf((acc[fr][fc][r] + bias) * sc);
                }
        }
    } else {
        // V transposed [B,H,64,N]: pack 4 contiguous tokens -> one 8B store
#pragma unroll
        for (int fc = 0; fc < 4; fc++) {
            int n = n0 + wn * 64 + fc * 16 + lr;
            float bias = qkv_b[n];
            int hh = (n >> 6) & 7, d = n & 63;
            ushort_t* dst = qkvb + ((((size_t)512 + bg) * 8 + hh) * 64 + d) * 256;
#pragma unroll
            for (int fr = 0; fr < 8; fr++) {
                int tok = wm * 128 + fr * 16 + lk * 4;
                uint2 pk;
                pk.x = (unsigned)f2bf(acc[fr][fc][0] + bias) |
                       ((unsigned)f2bf(acc[fr][fc][1] + bias) << 16);
                pk.y = (unsigned)f2bf(acc[fr][fc][2] + bias) |
                       ((unsigned)f2bf(acc[fr][fc][3] + bias) << 16);
                *reinterpret_cast<uint2*>(dst + tok) = pk;
            }
        }
    }
}

// ---------- attention: 512 threads per (bg,hh); 8 waves x 32 q-rows ----------
// Swapped QK^T (S^T) + register pipeline: K(kt+1) double-buffered in regs
// (full unroll -> static indices); rv(kt)/vb(kt) issued before QK so their
// latency hides under QK+softmax. hh-per-XCD swizzle: rpb slice L2-resident.
__global__ __launch_bounds__(512) void attn_kernel(
    const ushort_t* __restrict__ qkvb, const float* __restrict__ rpb,
    ushort_t* __restrict__ aout)
{
    __shared__ ushort_t Ps[8][32][40];          // wave-private P repack buffer
    __shared__ ushort_t Os[8][16 * 72];         // wave-private O store-repack buffer
    int t = threadIdx.x, lane = t & 63, w = t >> 6;
    int bid = blockIdx.x;                       // 2048 = B*H
    int wgid = (bid & 7) * 256 + (bid >> 3);    // XCD-contiguous
    int hh = wgid >> 8, bg = wgid & 255;        // one head per XCD
    const ushort_t* Qg  = qkvb + (((size_t)bg * 8 + hh) * 256) * 64;
    const ushort_t* Kg  = qkvb + (((size_t)(256 + bg) * 8 + hh) * 256) * 64;
    const ushort_t* VTg = qkvb + (((size_t)(512 + bg) * 8 + hh) * 64) * 256;  // [64][256]
    int lr = lane & 15, lk = lane >> 4;
    int qrow0 = w * 32;

    bf16x8 qf[2][2];
#pragma unroll
    for (int fr = 0; fr < 2; fr++)
#pragma unroll
        for (int kc = 0; kc < 2; kc++)
            qf[fr][kc] = *reinterpret_cast<const bf16x8*>(
                Qg + (size_t)(qrow0 + fr * 16 + lr) * 64 + kc * 32 + lk * 8);

    f32x4 oacc[2][4];
    float rsumq[2] = {0.f, 0.f};                // partial rowsum for q = qrow0+fq*16+lr
#pragma unroll
    for (int fr = 0; fr < 2; fr++)
#pragma unroll
        for (int fc = 0; fc < 4; fc++) oacc[fr][fc] = (f32x4){0.f, 0.f, 0.f, 0.f};

    const float* rpbh = rpb + (size_t)hh * 65536;

    // K register double-buffer [parity][kc][h]; full unroll -> all indices static
    bf16x8 kb[2][2][2];
#pragma unroll
    for (int kc = 0; kc < 2; kc++)
#pragma unroll
        for (int h = 0; h < 2; h++)
            kb[0][kc][h] = *reinterpret_cast<const bf16x8*>(
                Kg + (size_t)(h * 16 + lr) * 64 + kc * 32 + lk * 8);

#pragma unroll
    for (int kt = 0; kt < 8; ++kt) {
        const int cur = kt & 1, nxt = cur ^ 1;
        // issue next-K loads (land during this iteration's compute)
        if (kt < 7) {
#pragma unroll
            for (int kc = 0; kc < 2; kc++)
#pragma unroll
                for (int h = 0; h < 2; h++)
                    kb[nxt][kc][h] = *reinterpret_cast<const bf16x8*>(
                        Kg + (size_t)((kt + 1) * 32 + h * 16 + lr) * 64 + kc * 32 + lk * 8);
        }
        // issue rpb loads (needed after QK ~150cy) and V loads (needed after softmax)
        float4 rv[2][2];
#pragma unroll
        for (int fq = 0; fq < 2; fq++)
#pragma unroll
            for (int fk = 0; fk < 2; fk++)
                rv[fq][fk] = *reinterpret_cast<const float4*>(
                    rpbh + (size_t)(qrow0 + fq * 16 + lr) * 256 + kt * 32 + fk * 16 + lk * 4);
        bf16x8 vb[4];
#pragma unroll
        for (int fc = 0; fc < 4; fc++)
            vb[fc] = *reinterpret_cast<const bf16x8*>(
                VTg + (size_t)(fc * 16 + lr) * 256 + kt * 32 + lk * 8);

        // QK^T (swapped): sacc[fk][fq], D rows = k-tokens, cols = q
        f32x4 sacc[2][2];
#pragma unroll
        for (int fk = 0; fk < 2; fk++)
#pragma unroll
            for (int fq = 0; fq < 2; fq++) sacc[fk][fq] = (f32x4){0.f, 0.f, 0.f, 0.f};
#pragma unroll
        for (int kc = 0; kc < 2; kc++) {
            sacc[0][0] = MFMA16(kb[cur][kc][0], qf[0][kc], sacc[0][0]);
            sacc[0][1] = MFMA16(kb[cur][kc][0], qf[1][kc], sacc[0][1]);
            sacc[1][0] = MFMA16(kb[cur][kc][1], qf[0][kc], sacc[1][0]);
            sacc[1][1] = MFMA16(kb[cur][kc][1], qf[1][kc], sacc[1][1]);
        }
        // bias + exp + pack P (no max-subtract: logits bounded ~|2|)
#pragma unroll
        for (int fq = 0; fq < 2; fq++) {
#pragma unroll
            for (int fk = 0; fk < 2; fk++) {
                float p0 = __expf(sacc[fk][fq][0] + rv[fq][fk].x);
                float p1 = __expf(sacc[fk][fq][1] + rv[fq][fk].y);
                float p2 = __expf(sacc[fk][fq][2] + rv[fq][fk].z);
                float p3 = __expf(sacc[fk][fq][3] + rv[fq][fk].w);
                rsumq[fq] += (p0 + p1) + (p2 + p3);
                uint2 pk;
                pk.x = (unsigned)f2bf(p0) | ((unsigned)f2bf(p1) << 16);
                pk.y = (unsigned)f2bf(p2) | ((unsigned)f2bf(p3) << 16);
                *reinterpret_cast<uint2*>(&Ps[w][fq * 16 + lr][fk * 16 + lk * 4]) = pk;
            }
        }
        // PV (Ps layout [q][k] unchanged)
        bf16x8 pa[2];
#pragma unroll
        for (int fr = 0; fr < 2; fr++)
            pa[fr] = *reinterpret_cast<const bf16x8*>(&Ps[w][fr * 16 + lr][lk * 8]);
#pragma unroll
        for (int fr = 0; fr < 2; fr++)
#pragma unroll
            for (int fc = 0; fc < 4; fc++)
                oacc[fr][fc] = MFMA16(pa[fr], vb[fc], oacc[fr][fc]);
    }
    // finalize rowsum: reduce over lk-lanes, then redistribute per q-row
#pragma unroll
    for (int fq = 0; fq < 2; fq++) {
        float s = rsumq[fq];
        s += __shfl_xor(s, 16); s += __shfl_xor(s, 32);
        rsumq[fq] = __frcp_rn(s);
    }
    float rinv[2][4];
#pragma unroll
    for (int fr = 0; fr < 2; fr++)
#pragma unroll
        for (int r = 0; r < 4; r++)
            rinv[fr][r] = __shfl(rsumq[fr], lk * 4 + r);   // q-row fr*16+lk*4+r

    // O store via wave-private LDS repack -> 128B-contiguous per-token stores
#pragma unroll
    for (int fr = 0; fr < 2; fr++) {
#pragma unroll
        for (int fc = 0; fc < 4; fc++)
#pragma unroll
            for (int r = 0; r < 4; r++)
                Os[w][(lk * 4 + r) * 72 + fc * 16 + lr] = f2bf(oacc[fr][fc][r] * rinv[fr][r]);
#pragma unroll
        for (int ii = 0; ii < 2; ii++) {
            int j = lane + ii * 64;             // 128 chunks: 16 rows x 8 x 16B
            int row = j >> 3, ch = j & 7;
            uint4 v = *reinterpret_cast<const uint4*>(&Os[w][row * 72 + ch * 8]);
            *reinterpret_cast<uint4*>(
                aout + ((size_t)(bg * 256 + qrow0 + fr * 16 + row)) * 512 + hh * 64 + ch * 8) = v;
        }
    }
}

// ---------- proj GEMM: same 256x256/BK=64/8-wave template, fp32 out (round-8) ----------
__global__ __launch_bounds__(512, 1) void proj_gemm(
    const ushort_t* __restrict__ ain, const ushort_t* __restrict__ wT,
    const float* __restrict__ proj_b, float* __restrict__ out)
{
    __shared__ ushort_t As[2][256 * 64];
    __shared__ ushort_t Bs[2][256 * 64];
    int t = threadIdx.x;
    int bid = blockIdx.x;
    int wgid = (bid & 7) * 64 + (bid >> 3);     // 512 wgs, 64/XCD
    int mt = wgid / 2, nt = wgid % 2;
    int m0 = mt * 256, n0 = nt * 256;
    int lane = t & 63, w = t >> 6;
    int wm = w >> 2, wn = w & 3;
    int lr = lane & 15, lk = lane >> 4;
    int srow8 = lane >> 3;
    int sch = ((lane & 7) ^ srow8) * 8;
    const ushort_t* Asrc = ain + (size_t)(m0 + srow8) * 512 + sch;
    const ushort_t* Bsrc = wT + (size_t)(n0 + srow8) * 512 + sch;
    int arw = w & 3;
    int ch0 = ((lk) ^ (lr & 7)) * 8;
    int ch1 = ((4 + lk) ^ (lr & 7)) * 8;
    int arow = wm * 128 + lr;
    int brow = wn * 64 + lr;

    f32x4 acc[8][4];
#pragma unroll
    for (int fr = 0; fr < 8; fr++)
#pragma unroll
        for (int fc = 0; fc < 4; fc++) acc[fr][fc] = (f32x4){0.f, 0.f, 0.f, 0.f};

#define PSTAGE(buf, kt) do { \
    if (w < 4) { \
        _Pragma("unroll") \
        for (int i_ = 0; i_ < 8; i_++) { \
            int rb_ = arw * 64 + i_ * 8; \
            GLOAD16(Asrc + (size_t)rb_ * 512 + (kt) * 64, &As[buf][rb_ * 64]); \
        } \
    } else { \
        _Pragma("unroll") \
        for (int i_ = 0; i_ < 8; i_++) { \
            int rb_ = arw * 64 + i_ * 8; \
            GLOAD16(Bsrc + (size_t)rb_ * 512 + (kt) * 64, &Bs[buf][rb_ * 64]); \
        } \
    } } while (0)

    PSTAGE(0, 0);
    asm volatile("s_waitcnt vmcnt(0)" ::: "memory");
    __syncthreads();
    for (int kt = 0; kt < 8; ++kt) {
        int cb = kt & 1;
        if (kt < 7) PSTAGE(cb ^ 1, kt + 1);
#pragma unroll
        for (int kh = 0; kh < 2; kh++) {
            int ch = kh ? ch1 : ch0;
            bf16x8 a[8], b[4];
#pragma unroll
            for (int fr = 0; fr < 8; fr++)
                a[fr] = *reinterpret_cast<const bf16x8*>(&As[cb][(arow + fr * 16) * 64 + ch]);
#pragma unroll
            for (int fc = 0; fc < 4; fc++)
                b[fc] = *reinterpret_cast<const bf16x8*>(&Bs[cb][(brow + fc * 16) * 64 + ch]);
#pragma unroll
            for (int fr = 0; fr < 8; fr++)
#pragma unroll
                for (int fc = 0; fc < 4; fc++)
                    acc[fr][fc] = MFMA16(a[fr], b[fc], acc[fr][fc]);
        }
        if (kt < 7) {
            asm volatile("s_waitcnt vmcnt(0)" ::: "memory");
            __syncthreads();
        }
    }
#undef PSTAGE
#pragma unroll
    for (int fc = 0; fc < 4; fc++) {
        int n = n0 + wn * 64 + fc * 16 + lr;
        float bias = proj_b[n];
#pragma unroll
        for (int fr = 0; fr < 8; fr++)
#pragma unroll
            for (int r = 0; r < 4; r++) {
                int m = m0 + wm * 128 + fr * 16 + lk * 4 + r;
                out[(size_t)m * 512 + n] = acc[fr][fc][r] + bias;
            }
    }
}

extern "C" void kernel_launch(void* const* d_in, const int* in_sizes, int n_in,
                              void* d_out, int out_size, void* d_ws, size_t ws_size,
                              hipStream_t stream) {
    const float* x      = (const float*)d_in[0];
    const float* qkv_w  = (const float*)d_in[1];
    const float* qkv_b  = (const float*)d_in[2];
    const float* proj_w = (const float*)d_in[3];
    const float* proj_b = (const float*)d_in[4];
    const float* p1_w = (const float*)d_in[5];
    const float* p1_b = (const float*)d_in[6];
    const float* g1   = (const float*)d_in[7];
    const float* b1   = (const float*)d_in[8];
    const float* p2_w = (const float*)d_in[9];
    const float* p2_b = (const float*)d_in[10];
    const float* g2   = (const float*)d_in[11];
    const float* b2   = (const float*)d_in[12];
    const float* p3_w = (const float*)d_in[13];
    const float* p3_b = (const float*)d_in[14];
    const float* g3   = (const float*)d_in[15];
    const float* b3   = (const float*)d_in[16];
    const float* p4_w = (const float*)d_in[17];
    const float* p4_b = (const float*)d_in[18];
    const float* biases  = (const float*)d_in[19];
    const int*   rel_idx = (const int*)d_in[20];
    float* out = (float*)d_out;

    char* ws = (char*)d_ws;
    float*    pos    = (float*)(ws + POS_OFF);
    float*    rpb    = (float*)(ws + RPB_OFF);
    ushort_t* wqkvT  = (ushort_t*)(ws + WQKV_OFF);
    ushort_t* wprojT = (ushort_t*)(ws + WPROJ_OFF);
    ushort_t* qkvb   = (ushort_t*)(ws + QKV_OFF);
    ushort_t* aoutb  = (ushort_t*)(ws + AOUT_OFF);
    ushort_t* xb     = (ushort_t*)(ws + XB_OFF);     // overlays aoutb (disjoint lifetime)

    convert_x<<<dim3(16384), dim3(256), 0, stream>>>(x, xb);
    transpose_w<<<dim3(24 * 8), dim3(256), 0, stream>>>(qkv_w, wqkvT, 512, 1536);
    transpose_w<<<dim3(8 * 8), dim3(256), 0, stream>>>(proj_w, wprojT, 512, 512);
    pos_mlp<<<dim3(121), dim3(256), 0, stream>>>(biases, p1_w, p1_b, g1, b1,
                                                 p2_w, p2_b, g2, b2,
                                                 p3_w, p3_b, g3, b3,
                                                 p4_w, p4_b, pos);
    rpb_gather<<<dim3(256), dim3(256), 0, stream>>>(pos, rel_idx, rpb);
    qkv_gemm<<<dim3(1536), dim3(512), 0, stream>>>(xb, wqkvT, qkv_b, qkvb);
    attn_kernel<<<dim3(2048), dim3(512), 0, stream>>>(qkvb, rpb, aoutb);
    proj_gemm<<<dim3(512), dim3(512), 0, stream>>>(aoutb, wprojT, proj_b, out);
}

// Round 12
// 389.722 us; speedup vs baseline: 1.0990x; 1.0990x over previous
//
#include <hip/hip_runtime.h>
#include <stdint.h>

typedef __bf16 bf16x8 __attribute__((ext_vector_type(8)));
typedef float  f32x4  __attribute__((ext_vector_type(4)));
typedef unsigned short ushort_t;

#define MFMA16(a,b,c) __builtin_amdgcn_mfma_f32_16x16x32_bf16((a),(b),(c),0,0,0)

// async global->LDS, 16B per lane; LDS dest must be wave-uniform base (HW adds lane*16)
#define GLOAD16(gsrc, ldst) \
    __builtin_amdgcn_global_load_lds((const __attribute__((address_space(1))) void*)(gsrc), \
                                     (__attribute__((address_space(3))) void*)(ldst), 16, 0, 0)

// ---------- constants ----------
#define BATCH 256
#define NTOK  256
#define DIM   512
#define NH    8
#define HD    64
#define PD    32
#define LTAB  961

// workspace layout (bytes)
#define POS_OFF   0                         // 961*8*4
#define RPB_OFF   32768                     // 8*256*256*4 = 2 MB
#define WQKV_OFF  (RPB_OFF + 2097152)       // 1536*512*2
#define WPROJ_OFF (WQKV_OFF + 1572864)      // 512*512*2
#define QKV_OFF   (WPROJ_OFF + 524288)      // 3*256*8*256*64*2 = 192 MB
#define AOUT_OFF  (QKV_OFF + 201326592)     // 65536*512*2 = 64 MB
#define XB_OFF    AOUT_OFF                  // xb overlays aout: disjoint lifetimes

__device__ __forceinline__ ushort_t f2bf(float f) {
    unsigned int u = __builtin_bit_cast(unsigned int, f);
    u += 0x7FFFu + ((u >> 16) & 1u);
    return (ushort_t)(u >> 16);
}

// ---------- x fp32 -> bf16 ----------
__global__ __launch_bounds__(256) void convert_x(
    const float* __restrict__ x, ushort_t* __restrict__ xb)
{
    size_t i = ((size_t)blockIdx.x * 256 + threadIdx.x) * 8;
    float4 f0 = *(const float4*)(x + i);
    float4 f1 = *(const float4*)(x + i + 4);
    uint4 o;
    o.x = (unsigned)f2bf(f0.x) | ((unsigned)f2bf(f0.y) << 16);
    o.y = (unsigned)f2bf(f0.z) | ((unsigned)f2bf(f0.w) << 16);
    o.z = (unsigned)f2bf(f1.x) | ((unsigned)f2bf(f1.y) << 16);
    o.w = (unsigned)f2bf(f1.z) | ((unsigned)f2bf(f1.w) << 16);
    *reinterpret_cast<uint4*>(xb + i) = o;
}

// ---------- weight transpose + bf16 convert via LDS ----------
__global__ __launch_bounds__(256) void transpose_w(
    const float* __restrict__ src, ushort_t* __restrict__ dst, int K, int Nn)
{
    __shared__ ushort_t tile[64][65];
    int tiles_n = Nn >> 6;
    int tn = blockIdx.x % tiles_n, tk = blockIdx.x / tiles_n;
    int n0 = tn * 64, k0 = tk * 64;
    int t = threadIdx.x;
#pragma unroll
    for (int i = 0; i < 16; i++) {
        int idx = t + i * 256;
        int kl = idx >> 6, nl = idx & 63;
        tile[nl][kl] = f2bf(src[(size_t)(k0 + kl) * Nn + n0 + nl]);
    }
    __syncthreads();
#pragma unroll
    for (int i = 0; i < 16; i++) {
        int idx = t + i * 256;
        int nl = idx >> 6, kl = idx & 63;
        dst[(size_t)(n0 + nl) * K + k0 + kl] = tile[nl][kl];
    }
}

// ---------- dynamic position bias MLP ----------
__device__ __forceinline__ float ln_relu_t(float h, int j,
                                           const float* __restrict__ g,
                                           const float* __restrict__ bb) {
    float m = h;
    m += __shfl_xor(m, 1); m += __shfl_xor(m, 2); m += __shfl_xor(m, 4);
    m += __shfl_xor(m, 8); m += __shfl_xor(m, 16);
    m *= (1.0f / PD);
    float d = h - m;
    float v = d * d;
    v += __shfl_xor(v, 1); v += __shfl_xor(v, 2); v += __shfl_xor(v, 4);
    v += __shfl_xor(v, 8); v += __shfl_xor(v, 16);
    v *= (1.0f / PD);
    float x = d * rsqrtf(v + 1e-5f) * g[j] + bb[j];
    return x > 0.f ? x : 0.f;
}

__global__ __launch_bounds__(256) void pos_mlp(
    const float* __restrict__ biases,
    const float* __restrict__ p1_w, const float* __restrict__ p1_b,
    const float* __restrict__ g1, const float* __restrict__ b1,
    const float* __restrict__ p2_w, const float* __restrict__ p2_b,
    const float* __restrict__ g2, const float* __restrict__ b2,
    const float* __restrict__ p3_w, const float* __restrict__ p3_b,
    const float* __restrict__ g3, const float* __restrict__ b3,
    const float* __restrict__ p4_w, const float* __restrict__ p4_b,
    float* __restrict__ pos)
{
    __shared__ float hs[8][33];
    int tid = threadIdx.x;
    int rl = tid >> 5, j = tid & 31;
    int r = blockIdx.x * 8 + rl;
    bool ok = r < LTAB;
    float c0 = ok ? biases[r * 2 + 0] : 0.f;
    float c1 = ok ? biases[r * 2 + 1] : 0.f;

    float h = c0 * p1_w[j] + c1 * p1_w[PD + j] + p1_b[j];
    h = ln_relu_t(h, j, g1, b1);

    hs[rl][j] = h;
    __syncthreads();
    float s = p2_b[j];
#pragma unroll
    for (int i = 0; i < PD; i++) s += hs[rl][i] * p2_w[i * PD + j];
    __syncthreads();
    h = ln_relu_t(s, j, g2, b2);

    hs[rl][j] = h;
    __syncthreads();
    s = p3_b[j];
#pragma unroll
    for (int i = 0; i < PD; i++) s += hs[rl][i] * p3_w[i * PD + j];
    __syncthreads();
    h = ln_relu_t(s, j, g3, b3);

    hs[rl][j] = h;
    __syncthreads();
    if (ok && j < NH) {
        float o = p4_b[j];
#pragma unroll
        for (int i = 0; i < PD; i++) o += hs[rl][i] * p4_w[i * NH + j];
        pos[r * NH + j] = o;
    }
}

// ---------- rpb gather ----------
__global__ __launch_bounds__(256) void rpb_gather(
    const float* __restrict__ pos, const int* __restrict__ rel_idx,
    float* __restrict__ rpb)
{
    int i = blockIdx.x * 256 + threadIdx.x;   // < 65536
    int idx = rel_idx[i];
#pragma unroll
    for (int hh = 0; hh < NH; hh++) rpb[(size_t)hh * 65536 + i] = pos[idx * NH + hh];
}

// ---------- QKV GEMM: 256x256 tile, BK=64, 8 waves, dbuf 2-phase (round-8 best) ----------
__global__ __launch_bounds__(512, 1) void qkv_gemm(
    const ushort_t* __restrict__ xb, const ushort_t* __restrict__ wT,
    const float* __restrict__ qkv_b, ushort_t* __restrict__ qkvb)
{
    __shared__ ushort_t As[2][256 * 64];   // 32 KB each buf
    __shared__ ushort_t Bs[2][256 * 64];
    int t = threadIdx.x;
    int bid = blockIdx.x;
    int wgid = (bid & 7) * 192 + (bid >> 3);    // 1536 wgs, 192/XCD
    int mt = wgid / 6, nt = wgid % 6;           // n fastest within XCD chunk
    int m0 = mt * 256, n0 = nt * 256;
    int lane = t & 63, w = t >> 6;              // 8 waves
    int wm = w >> 2, wn = w & 3;                // 2M x 4N wave grid, wave out 128x64
    int lr = lane & 15, lk = lane >> 4;
    int srow8 = lane >> 3;
    int sch = ((lane & 7) ^ srow8) * 8;         // pre-swizzled source chunk
    const ushort_t* Asrc = xb + (size_t)(m0 + srow8) * 512 + sch;
    const ushort_t* Bsrc = wT + (size_t)(n0 + srow8) * 512 + sch;
    int arw = w & 3;
    int ch0 = ((lk) ^ (lr & 7)) * 8;
    int ch1 = ((4 + lk) ^ (lr & 7)) * 8;
    int arow = wm * 128 + lr;
    int brow = wn * 64 + lr;

    f32x4 acc[8][4];
#pragma unroll
    for (int fr = 0; fr < 8; fr++)
#pragma unroll
        for (int fc = 0; fc < 4; fc++) acc[fr][fc] = (f32x4){0.f, 0.f, 0.f, 0.f};

#define QSTAGE(buf, kt) do { \
    if (w < 4) { \
        _Pragma("unroll") \
        for (int i_ = 0; i_ < 8; i_++) { \
            int rb_ = arw * 64 + i_ * 8; \
            GLOAD16(Asrc + (size_t)rb_ * 512 + (kt) * 64, &As[buf][rb_ * 64]); \
        } \
    } else { \
        _Pragma("unroll") \
        for (int i_ = 0; i_ < 8; i_++) { \
            int rb_ = arw * 64 + i_ * 8; \
            GLOAD16(Bsrc + (size_t)rb_ * 512 + (kt) * 64, &Bs[buf][rb_ * 64]); \
        } \
    } } while (0)

    QSTAGE(0, 0);
    asm volatile("s_waitcnt vmcnt(0)" ::: "memory");
    __syncthreads();
    for (int kt = 0; kt < 8; ++kt) {
        int cb = kt & 1;
        if (kt < 7) QSTAGE(cb ^ 1, kt + 1);     // latency hides under compute below
#pragma unroll
        for (int kh = 0; kh < 2; kh++) {
            int ch = kh ? ch1 : ch0;
            bf16x8 a[8], b[4];
#pragma unroll
            for (int fr = 0; fr < 8; fr++)
                a[fr] = *reinterpret_cast<const bf16x8*>(&As[cb][(arow + fr * 16) * 64 + ch]);
#pragma unroll
            for (int fc = 0; fc < 4; fc++)
                b[fc] = *reinterpret_cast<const bf16x8*>(&Bs[cb][(brow + fc * 16) * 64 + ch]);
#pragma unroll
            for (int fr = 0; fr < 8; fr++)
#pragma unroll
                for (int fc = 0; fc < 4; fc++)
                    acc[fr][fc] = MFMA16(a[fr], b[fc], acc[fr][fc]);
        }
        if (kt < 7) {
            asm volatile("s_waitcnt vmcnt(0)" ::: "memory");
            __syncthreads();
        }
    }
#undef QSTAGE

    // epilogue: s = q/k/v uniform per block; bg uniform (m0 mult of 256)
    int s = n0 >> 9;
    int bg = m0 >> 8;
    if (s < 2) {
        float sc = (s == 0) ? 0.125f : 1.0f;
#pragma unroll
        for (int fc = 0; fc < 4; fc++) {
            int n = n0 + wn * 64 + fc * 16 + lr;
            float bias = qkv_b[n];
            int hh = (n >> 6) & 7, d = n & 63;
            ushort_t* dst = qkvb + ((((size_t)s * 256 + bg) * 8 + hh) * 256) * 64 + d;
#pragma unroll
            for (int fr = 0; fr < 8; fr++)
#pragma unroll
                for (int r = 0; r < 4; r++) {
                    int tok = wm * 128 + fr * 16 + lk * 4 + r;
                    dst[(size_t)tok * 64] = f2bf((acc[fr][fc][r] + bias) * sc);
                }
        }
    } else {
        // V transposed [B,H,64,N]: pack 4 contiguous tokens -> one 8B store
#pragma unroll
        for (int fc = 0; fc < 4; fc++) {
            int n = n0 + wn * 64 + fc * 16 + lr;
            float bias = qkv_b[n];
            int hh = (n >> 6) & 7, d = n & 63;
            ushort_t* dst = qkvb + ((((size_t)512 + bg) * 8 + hh) * 64 + d) * 256;
#pragma unroll
            for (int fr = 0; fr < 8; fr++) {
                int tok = wm * 128 + fr * 16 + lk * 4;
                uint2 pk;
                pk.x = (unsigned)f2bf(acc[fr][fc][0] + bias) |
                       ((unsigned)f2bf(acc[fr][fc][1] + bias) << 16);
                pk.y = (unsigned)f2bf(acc[fr][fc][2] + bias) |
                       ((unsigned)f2bf(acc[fr][fc][3] + bias) << 16);
                *reinterpret_cast<uint2*>(dst + tok) = pk;
            }
        }
    }
}

// ---------- attention: R8-original structure + hh-per-XCD swizzle + setprio ----------
// per (b,h,half-128-rows); waves independent, 32 rows each.
__global__ __launch_bounds__(256) void attn_kernel(
    const ushort_t* __restrict__ qkvb, const float* __restrict__ rpb,
    ushort_t* __restrict__ aout)
{
    __shared__ ushort_t Ps[4][32][40];          // wave-private P repack buffer
    __shared__ ushort_t Os[4][16 * 72];         // wave-private O store-repack buffer
    int t = threadIdx.x, lane = t & 63, w = t >> 6;
    int bid = blockIdx.x;                       // 4096 = H * B * 2
    int wgid = (bid & 7) * 512 + (bid >> 3);    // one head per XCD (512 blocks each)
    int hh = wgid >> 9;                         // 0..7
    int bg = (wgid >> 1) & 255;
    int qh = wgid & 1;
    const ushort_t* Qg  = qkvb + (((size_t)bg * 8 + hh) * 256) * 64;
    const ushort_t* Kg  = qkvb + (((size_t)(256 + bg) * 8 + hh) * 256) * 64;
    const ushort_t* VTg = qkvb + (((size_t)(512 + bg) * 8 + hh) * 64) * 256;  // [64][256]
    int lr = lane & 15, lk = lane >> 4;
    int qrow0 = qh * 128 + w * 32;

    bf16x8 qf[2][2];
#pragma unroll
    for (int fr = 0; fr < 2; fr++)
#pragma unroll
        for (int kc = 0; kc < 2; kc++)
            qf[fr][kc] = *reinterpret_cast<const bf16x8*>(
                Qg + (size_t)(qrow0 + fr * 16 + lr) * 64 + kc * 32 + lk * 8);

    f32x4 oacc[2][4];
    float rsum[2][4];
#pragma unroll
    for (int fr = 0; fr < 2; fr++) {
#pragma unroll
        for (int fc = 0; fc < 4; fc++) oacc[fr][fc] = (f32x4){0.f, 0.f, 0.f, 0.f};
#pragma unroll
        for (int r = 0; r < 4; r++) rsum[fr][r] = 0.f;
    }

    for (int kt = 0; kt < 8; ++kt) {
        f32x4 sacc[2][2];
#pragma unroll
        for (int fr = 0; fr < 2; fr++)
#pragma unroll
            for (int fc = 0; fc < 2; fc++) sacc[fr][fc] = (f32x4){0.f, 0.f, 0.f, 0.f};
        __builtin_amdgcn_s_setprio(1);
#pragma unroll
        for (int kc = 0; kc < 2; kc++) {
            bf16x8 kb0 = *reinterpret_cast<const bf16x8*>(
                Kg + (size_t)(kt * 32 + lr) * 64 + kc * 32 + lk * 8);
            bf16x8 kb1 = *reinterpret_cast<const bf16x8*>(
                Kg + (size_t)(kt * 32 + 16 + lr) * 64 + kc * 32 + lk * 8);
            sacc[0][0] = MFMA16(qf[0][kc], kb0, sacc[0][0]);
            sacc[0][1] = MFMA16(qf[0][kc], kb1, sacc[0][1]);
            sacc[1][0] = MFMA16(qf[1][kc], kb0, sacc[1][0]);
            sacc[1][1] = MFMA16(qf[1][kc], kb1, sacc[1][1]);
        }
        __builtin_amdgcn_s_setprio(0);
        // bias + exp + pack P (no max-subtract: logits bounded ~|2|)
#pragma unroll
        for (int fr = 0; fr < 2; fr++)
#pragma unroll
            for (int fc = 0; fc < 2; fc++)
#pragma unroll
                for (int r = 0; r < 4; r++) {
                    int row = qrow0 + fr * 16 + lk * 4 + r;
                    int col = kt * 32 + fc * 16 + lr;
                    float lg = sacc[fr][fc][r] + rpb[((size_t)hh * 256 + row) * 256 + col];
                    float p = __expf(lg);
                    rsum[fr][r] += p;
                    Ps[w][fr * 16 + lk * 4 + r][fc * 16 + lr] = f2bf(p);
                }
        // PV
        bf16x8 pa[2], vb[4];
#pragma unroll
        for (int fr = 0; fr < 2; fr++)
            pa[fr] = *reinterpret_cast<const bf16x8*>(&Ps[w][fr * 16 + lr][lk * 8]);
#pragma unroll
        for (int fc = 0; fc < 4; fc++)
            vb[fc] = *reinterpret_cast<const bf16x8*>(
                VTg + (size_t)(fc * 16 + lr) * 256 + kt * 32 + lk * 8);
        __builtin_amdgcn_s_setprio(1);
#pragma unroll
        for (int fr = 0; fr < 2; fr++)
#pragma unroll
            for (int fc = 0; fc < 4; fc++)
                oacc[fr][fc] = MFMA16(pa[fr], vb[fc], oacc[fr][fc]);
        __builtin_amdgcn_s_setprio(0);
    }
    // reduce rowsum over lanes 0..15 (lr bits), reciprocal
    float rinv[2][4];
#pragma unroll
    for (int fr = 0; fr < 2; fr++)
#pragma unroll
        for (int r = 0; r < 4; r++) {
            float s = rsum[fr][r];
            s += __shfl_xor(s, 1); s += __shfl_xor(s, 2);
            s += __shfl_xor(s, 4); s += __shfl_xor(s, 8);
            rinv[fr][r] = __frcp_rn(s);
        }
    // O store via wave-private LDS repack -> 128B-contiguous per-token stores
#pragma unroll
    for (int fr = 0; fr < 2; fr++) {
#pragma unroll
        for (int fc = 0; fc < 4; fc++)
#pragma unroll
            for (int r = 0; r < 4; r++)
                Os[w][(lk * 4 + r) * 72 + fc * 16 + lr] = f2bf(oacc[fr][fc][r] * rinv[fr][r]);
#pragma unroll
        for (int ii = 0; ii < 2; ii++) {
            int j = lane + ii * 64;             // 128 chunks: 16 rows x 8 x 16B
            int row = j >> 3, ch = j & 7;
            uint4 v = *reinterpret_cast<const uint4*>(&Os[w][row * 72 + ch * 8]);
            *reinterpret_cast<uint4*>(
                aout + ((size_t)(bg * 256 + qrow0 + fr * 16 + row)) * 512 + hh * 64 + ch * 8) = v;
        }
    }
}

// ---------- proj GEMM: same 256x256/BK=64/8-wave template, fp32 out (round-8) ----------
__global__ __launch_bounds__(512, 1) void proj_gemm(
    const ushort_t* __restrict__ ain, const ushort_t* __restrict__ wT,
    const float* __restrict__ proj_b, float* __restrict__ out)
{
    __shared__ ushort_t As[2][256 * 64];
    __shared__ ushort_t Bs[2][256 * 64];
    int t = threadIdx.x;
    int bid = blockIdx.x;
    int wgid = (bid & 7) * 64 + (bid >> 3);     // 512 wgs, 64/XCD
    int mt = wgid / 2, nt = wgid % 2;
    int m0 = mt * 256, n0 = nt * 256;
    int lane = t & 63, w = t >> 6;
    int wm = w >> 2, wn = w & 3;
    int lr = lane & 15, lk = lane >> 4;
    int srow8 = lane >> 3;
    int sch = ((lane & 7) ^ srow8) * 8;
    const ushort_t* Asrc = ain + (size_t)(m0 + srow8) * 512 + sch;
    const ushort_t* Bsrc = wT + (size_t)(n0 + srow8) * 512 + sch;
    int arw = w & 3;
    int ch0 = ((lk) ^ (lr & 7)) * 8;
    int ch1 = ((4 + lk) ^ (lr & 7)) * 8;
    int arow = wm * 128 + lr;
    int brow = wn * 64 + lr;

    f32x4 acc[8][4];
#pragma unroll
    for (int fr = 0; fr < 8; fr++)
#pragma unroll
        for (int fc = 0; fc < 4; fc++) acc[fr][fc] = (f32x4){0.f, 0.f, 0.f, 0.f};

#define PSTAGE(buf, kt) do { \
    if (w < 4) { \
        _Pragma("unroll") \
        for (int i_ = 0; i_ < 8; i_++) { \
            int rb_ = arw * 64 + i_ * 8; \
            GLOAD16(Asrc + (size_t)rb_ * 512 + (kt) * 64, &As[buf][rb_ * 64]); \
        } \
    } else { \
        _Pragma("unroll") \
        for (int i_ = 0; i_ < 8; i_++) { \
            int rb_ = arw * 64 + i_ * 8; \
            GLOAD16(Bsrc + (size_t)rb_ * 512 + (kt) * 64, &Bs[buf][rb_ * 64]); \
        } \
    } } while (0)

    PSTAGE(0, 0);
    asm volatile("s_waitcnt vmcnt(0)" ::: "memory");
    __syncthreads();
    for (int kt = 0; kt < 8; ++kt) {
        int cb = kt & 1;
        if (kt < 7) PSTAGE(cb ^ 1, kt + 1);
#pragma unroll
        for (int kh = 0; kh < 2; kh++) {
            int ch = kh ? ch1 : ch0;
            bf16x8 a[8], b[4];
#pragma unroll
            for (int fr = 0; fr < 8; fr++)
                a[fr] = *reinterpret_cast<const bf16x8*>(&As[cb][(arow + fr * 16) * 64 + ch]);
#pragma unroll
            for (int fc = 0; fc < 4; fc++)
                b[fc] = *reinterpret_cast<const bf16x8*>(&Bs[cb][(brow + fc * 16) * 64 + ch]);
#pragma unroll
            for (int fr = 0; fr < 8; fr++)
#pragma unroll
                for (int fc = 0; fc < 4; fc++)
                    acc[fr][fc] = MFMA16(a[fr], b[fc], acc[fr][fc]);
        }
        if (kt < 7) {
            asm volatile("s_waitcnt vmcnt(0)" ::: "memory");
            __syncthreads();
        }
    }
#undef PSTAGE
#pragma unroll
    for (int fc = 0; fc < 4; fc++) {
        int n = n0 + wn * 64 + fc * 16 + lr;
        float bias = proj_b[n];
#pragma unroll
        for (int fr = 0; fr < 8; fr++)
#pragma unroll
            for (int r = 0; r < 4; r++) {
                int m = m0 + wm * 128 + fr * 16 + lk * 4 + r;
                out[(size_t)m * 512 + n] = acc[fr][fc][r] + bias;
            }
    }
}

extern "C" void kernel_launch(void* const* d_in, const int* in_sizes, int n_in,
                              void* d_out, int out_size, void* d_ws, size_t ws_size,
                              hipStream_t stream) {
    const float* x      = (const float*)d_in[0];
    const float* qkv_w  = (const float*)d_in[1];
    const float* qkv_b  = (const float*)d_in[2];
    const float* proj_w = (const float*)d_in[3];
    const float* proj_b = (const float*)d_in[4];
    const float* p1_w = (const float*)d_in[5];
    const float* p1_b = (const float*)d_in[6];
    const float* g1   = (const float*)d_in[7];
    const float* b1   = (const float*)d_in[8];
    const float* p2_w = (const float*)d_in[9];
    const float* p2_b = (const float*)d_in[10];
    const float* g2   = (const float*)d_in[11];
    const float* b2   = (const float*)d_in[12];
    const float* p3_w = (const float*)d_in[13];
    const float* p3_b = (const float*)d_in[14];
    const float* g3   = (const float*)d_in[15];
    const float* b3   = (const float*)d_in[16];
    const float* p4_w = (const float*)d_in[17];
    const float* p4_b = (const float*)d_in[18];
    const float* biases  = (const float*)d_in[19];
    const int*   rel_idx = (const int*)d_in[20];
    float* out = (float*)d_out;

    char* ws = (char*)d_ws;
    float*    pos    = (float*)(ws + POS_OFF);
    float*    rpb    = (float*)(ws + RPB_OFF);
    ushort_t* wqkvT  = (ushort_t*)(ws + WQKV_OFF);
    ushort_t* wprojT = (ushort_t*)(ws + WPROJ_OFF);
    ushort_t* qkvb   = (ushort_t*)(ws + QKV_OFF);
    ushort_t* aoutb  = (ushort_t*)(ws + AOUT_OFF);
    ushort_t* xb     = (ushort_t*)(ws + XB_OFF);     // overlays aoutb (disjoint lifetime)

    convert_x<<<dim3(16384), dim3(256), 0, stream>>>(x, xb);
    transpose_w<<<dim3(24 * 8), dim3(256), 0, stream>>>(qkv_w, wqkvT, 512, 1536);
    transpose_w<<<dim3(8 * 8), dim3(256), 0, stream>>>(proj_w, wprojT, 512, 512);
    pos_mlp<<<dim3(121), dim3(256), 0, stream>>>(biases, p1_w, p1_b, g1, b1,
                                                 p2_w, p2_b, g2, b2,
                                                 p3_w, p3_b, g3, b3,
                                                 p4_w, p4_b, pos);
    rpb_gather<<<dim3(256), dim3(256), 0, stream>>>(pos, rel_idx, rpb);
    qkv_gemm<<<dim3(1536), dim3(512), 0, stream>>>(xb, wqkvT, qkv_b, qkvb);
    attn_kernel<<<dim3(4096), dim3(256), 0, stream>>>(qkvb, rpb, aoutb);
    proj_gemm<<<dim3(512), dim3(512), 0, stream>>>(aoutb, wprojT, proj_b, out);
}

// Round 13
// 369.697 us; speedup vs baseline: 1.1585x; 1.0542x over previous
//
#include <hip/hip_runtime.h>
#include <stdint.h>

typedef __bf16 bf16x8 __attribute__((ext_vector_type(8)));
typedef float  f32x4  __attribute__((ext_vector_type(4)));
typedef unsigned short ushort_t;

#define MFMA16(a,b,c) __builtin_amdgcn_mfma_f32_16x16x32_bf16((a),(b),(c),0,0,0)

// async global->LDS, 16B per lane; LDS dest must be wave-uniform base (HW adds lane*16)
#define GLOAD16(gsrc, ldst) \
    __builtin_amdgcn_global_load_lds((const __attribute__((address_space(1))) void*)(gsrc), \
                                     (__attribute__((address_space(3))) void*)(ldst), 16, 0, 0)

// ---------- constants ----------
#define BATCH 256
#define NTOK  256
#define DIM   512
#define NH    8
#define HD    64
#define PD    32
#define LTAB  961

// workspace layout (bytes)
#define POS_OFF   0                         // 961*8*4
#define RPB_OFF   32768                     // 8*256*256*4 = 2 MB
#define WQKV_OFF  (RPB_OFF + 2097152)       // 1536*512*2
#define WPROJ_OFF (WQKV_OFF + 1572864)      // 512*512*2
#define QKV_OFF   (WPROJ_OFF + 524288)      // 3*256*8*256*64*2 = 192 MB
#define AOUT_OFF  (QKV_OFF + 201326592)     // 65536*512*2 = 64 MB
#define XB_OFF    AOUT_OFF                  // xb overlays aout: disjoint lifetimes

__device__ __forceinline__ ushort_t f2bf(float f) {
    unsigned int u = __builtin_bit_cast(unsigned int, f);
    u += 0x7FFFu + ((u >> 16) & 1u);
    return (ushort_t)(u >> 16);
}

// ---------- fused prologue: convert_x | transpose_w(qkv) | transpose_w(proj) | pos_mlp ----------
// block ranges: [0,16384) convert_x; [16384,16576) t_qkv; [16576,16640) t_proj; [16640,16761) pos_mlp
#define PRO_CONV  16384
#define PRO_TQKV  (PRO_CONV + 192)
#define PRO_TPROJ (PRO_TQKV + 64)
#define PRO_TOTAL (PRO_TPROJ + 121)

__device__ __forceinline__ void transpose_body(
    const float* __restrict__ src, ushort_t* __restrict__ dst,
    int K, int Nn, int bid, int t, ushort_t (*tile)[65])
{
    int tiles_n = Nn >> 6;
    int tn = bid % tiles_n, tk = bid / tiles_n;
    int n0 = tn * 64, k0 = tk * 64;
#pragma unroll
    for (int i = 0; i < 16; i++) {
        int idx = t + i * 256;
        int kl = idx >> 6, nl = idx & 63;
        tile[nl][kl] = f2bf(src[(size_t)(k0 + kl) * Nn + n0 + nl]);
    }
    __syncthreads();
#pragma unroll
    for (int i = 0; i < 16; i++) {
        int idx = t + i * 256;
        int nl = idx >> 6, kl = idx & 63;
        dst[(size_t)(n0 + nl) * K + k0 + kl] = tile[nl][kl];
    }
}

__device__ __forceinline__ float ln_relu_t(float h, int j,
                                           const float* __restrict__ g,
                                           const float* __restrict__ bb) {
    float m = h;
    m += __shfl_xor(m, 1); m += __shfl_xor(m, 2); m += __shfl_xor(m, 4);
    m += __shfl_xor(m, 8); m += __shfl_xor(m, 16);
    m *= (1.0f / PD);
    float d = h - m;
    float v = d * d;
    v += __shfl_xor(v, 1); v += __shfl_xor(v, 2); v += __shfl_xor(v, 4);
    v += __shfl_xor(v, 8); v += __shfl_xor(v, 16);
    v *= (1.0f / PD);
    float x = d * rsqrtf(v + 1e-5f) * g[j] + bb[j];
    return x > 0.f ? x : 0.f;
}

__global__ __launch_bounds__(256) void prologue(
    const float* __restrict__ x, ushort_t* __restrict__ xb,
    const float* __restrict__ qkv_w, ushort_t* __restrict__ wqkvT,
    const float* __restrict__ proj_w, ushort_t* __restrict__ wprojT,
    const float* __restrict__ biases,
    const float* __restrict__ p1_w, const float* __restrict__ p1_b,
    const float* __restrict__ g1, const float* __restrict__ b1,
    const float* __restrict__ p2_w, const float* __restrict__ p2_b,
    const float* __restrict__ g2, const float* __restrict__ b2,
    const float* __restrict__ p3_w, const float* __restrict__ p3_b,
    const float* __restrict__ g3, const float* __restrict__ b3,
    const float* __restrict__ p4_w, const float* __restrict__ p4_b,
    float* __restrict__ pos)
{
    __shared__ ushort_t tile[64][65];
    __shared__ float hs[8][33];
    int b = blockIdx.x, tid = threadIdx.x;
    if (b < PRO_CONV) {
        size_t i = ((size_t)b * 256 + tid) * 8;
        float4 f0 = *(const float4*)(x + i);
        float4 f1 = *(const float4*)(x + i + 4);
        uint4 o;
        o.x = (unsigned)f2bf(f0.x) | ((unsigned)f2bf(f0.y) << 16);
        o.y = (unsigned)f2bf(f0.z) | ((unsigned)f2bf(f0.w) << 16);
        o.z = (unsigned)f2bf(f1.x) | ((unsigned)f2bf(f1.y) << 16);
        o.w = (unsigned)f2bf(f1.z) | ((unsigned)f2bf(f1.w) << 16);
        *reinterpret_cast<uint4*>(xb + i) = o;
    } else if (b < PRO_TQKV) {
        transpose_body(qkv_w, wqkvT, 512, 1536, b - PRO_CONV, tid, tile);
    } else if (b < PRO_TPROJ) {
        transpose_body(proj_w, wprojT, 512, 512, b - PRO_TQKV, tid, tile);
    } else {
        int rl = tid >> 5, j = tid & 31;
        int r = (b - PRO_TPROJ) * 8 + rl;
        bool ok = r < LTAB;
        float c0 = ok ? biases[r * 2 + 0] : 0.f;
        float c1 = ok ? biases[r * 2 + 1] : 0.f;

        float h = c0 * p1_w[j] + c1 * p1_w[PD + j] + p1_b[j];
        h = ln_relu_t(h, j, g1, b1);

        hs[rl][j] = h;
        __syncthreads();
        float s = p2_b[j];
#pragma unroll
        for (int i = 0; i < PD; i++) s += hs[rl][i] * p2_w[i * PD + j];
        __syncthreads();
        h = ln_relu_t(s, j, g2, b2);

        hs[rl][j] = h;
        __syncthreads();
        s = p3_b[j];
#pragma unroll
        for (int i = 0; i < PD; i++) s += hs[rl][i] * p3_w[i * PD + j];
        __syncthreads();
        h = ln_relu_t(s, j, g3, b3);

        hs[rl][j] = h;
        __syncthreads();
        if (ok && j < NH) {
            float o = p4_b[j];
#pragma unroll
            for (int i = 0; i < PD; i++) o += hs[rl][i] * p4_w[i * NH + j];
            pos[r * NH + j] = o;
        }
    }
}

// ---------- rpb gather ----------
__global__ __launch_bounds__(256) void rpb_gather(
    const float* __restrict__ pos, const int* __restrict__ rel_idx,
    float* __restrict__ rpb)
{
    int i = blockIdx.x * 256 + threadIdx.x;   // < 65536
    int idx = rel_idx[i];
#pragma unroll
    for (int hh = 0; hh < NH; hh++) rpb[(size_t)hh * 65536 + i] = pos[idx * NH + hh];
}

// ---------- QKV GEMM: 256x256 tile, BK=64, 8 waves, dbuf 2-phase (round-8 best) ----------
__global__ __launch_bounds__(512, 1) void qkv_gemm(
    const ushort_t* __restrict__ xb, const ushort_t* __restrict__ wT,
    const float* __restrict__ qkv_b, ushort_t* __restrict__ qkvb)
{
    __shared__ ushort_t As[2][256 * 64];   // 32 KB each buf
    __shared__ ushort_t Bs[2][256 * 64];
    int t = threadIdx.x;
    int bid = blockIdx.x;
    int wgid = (bid & 7) * 192 + (bid >> 3);    // 1536 wgs, 192/XCD
    int mt = wgid / 6, nt = wgid % 6;           // n fastest within XCD chunk
    int m0 = mt * 256, n0 = nt * 256;
    int lane = t & 63, w = t >> 6;              // 8 waves
    int wm = w >> 2, wn = w & 3;                // 2M x 4N wave grid, wave out 128x64
    int lr = lane & 15, lk = lane >> 4;
    int srow8 = lane >> 3;
    int sch = ((lane & 7) ^ srow8) * 8;         // pre-swizzled source chunk
    const ushort_t* Asrc = xb + (size_t)(m0 + srow8) * 512 + sch;
    const ushort_t* Bsrc = wT + (size_t)(n0 + srow8) * 512 + sch;
    int arw = w & 3;
    int ch0 = ((lk) ^ (lr & 7)) * 8;
    int ch1 = ((4 + lk) ^ (lr & 7)) * 8;
    int arow = wm * 128 + lr;
    int brow = wn * 64 + lr;

    f32x4 acc[8][4];
#pragma unroll
    for (int fr = 0; fr < 8; fr++)
#pragma unroll
        for (int fc = 0; fc < 4; fc++) acc[fr][fc] = (f32x4){0.f, 0.f, 0.f, 0.f};

#define QSTAGE(buf, kt) do { \
    if (w < 4) { \
        _Pragma("unroll") \
        for (int i_ = 0; i_ < 8; i_++) { \
            int rb_ = arw * 64 + i_ * 8; \
            GLOAD16(Asrc + (size_t)rb_ * 512 + (kt) * 64, &As[buf][rb_ * 64]); \
        } \
    } else { \
        _Pragma("unroll") \
        for (int i_ = 0; i_ < 8; i_++) { \
            int rb_ = arw * 64 + i_ * 8; \
            GLOAD16(Bsrc + (size_t)rb_ * 512 + (kt) * 64, &Bs[buf][rb_ * 64]); \
        } \
    } } while (0)

    QSTAGE(0, 0);
    asm volatile("s_waitcnt vmcnt(0)" ::: "memory");
    __syncthreads();
    for (int kt = 0; kt < 8; ++kt) {
        int cb = kt & 1;
        if (kt < 7) QSTAGE(cb ^ 1, kt + 1);     // latency hides under compute below
#pragma unroll
        for (int kh = 0; kh < 2; kh++) {
            int ch = kh ? ch1 : ch0;
            bf16x8 a[8], b[4];
#pragma unroll
            for (int fr = 0; fr < 8; fr++)
                a[fr] = *reinterpret_cast<const bf16x8*>(&As[cb][(arow + fr * 16) * 64 + ch]);
#pragma unroll
            for (int fc = 0; fc < 4; fc++)
                b[fc] = *reinterpret_cast<const bf16x8*>(&Bs[cb][(brow + fc * 16) * 64 + ch]);
#pragma unroll
            for (int fr = 0; fr < 8; fr++)
#pragma unroll
                for (int fc = 0; fc < 4; fc++)
                    acc[fr][fc] = MFMA16(a[fr], b[fc], acc[fr][fc]);
        }
        if (kt < 7) {
            asm volatile("s_waitcnt vmcnt(0)" ::: "memory");
            __syncthreads();
        }
    }
#undef QSTAGE

    // epilogue: s = q/k/v uniform per block; bg uniform (m0 mult of 256)
    int s = n0 >> 9;
    int bg = m0 >> 8;
    if (s < 2) {
        float sc = (s == 0) ? 0.125f : 1.0f;
#pragma unroll
        for (int fc = 0; fc < 4; fc++) {
            int n = n0 + wn * 64 + fc * 16 + lr;
            float bias = qkv_b[n];
            int hh = (n >> 6) & 7, d = n & 63;
            ushort_t* dst = qkvb + ((((size_t)s * 256 + bg) * 8 + hh) * 256) * 64 + d;
#pragma unroll
            for (int fr = 0; fr < 8; fr++)
#pragma unroll
                for (int r = 0; r < 4; r++) {
                    int tok = wm * 128 + fr * 16 + lk * 4 + r;
                    dst[(size_t)tok * 64] = f2bf((acc[fr][fc][r] + bias) * sc);
                }
        }
    } else {
        // V transposed [B,H,64,N]: pack 4 contiguous tokens -> one 8B store
#pragma unroll
        for (int fc = 0; fc < 4; fc++) {
            int n = n0 + wn * 64 + fc * 16 + lr;
            float bias = qkv_b[n];
            int hh = (n >> 6) & 7, d = n & 63;
            ushort_t* dst = qkvb + ((((size_t)512 + bg) * 8 + hh) * 64 + d) * 256;
#pragma unroll
            for (int fr = 0; fr < 8; fr++) {
                int tok = wm * 128 + fr * 16 + lk * 4;
                uint2 pk;
                pk.x = (unsigned)f2bf(acc[fr][fc][0] + bias) |
                       ((unsigned)f2bf(acc[fr][fc][1] + bias) << 16);
                pk.y = (unsigned)f2bf(acc[fr][fc][2] + bias) |
                       ((unsigned)f2bf(acc[fr][fc][3] + bias) << 16);
                *reinterpret_cast<uint2*>(dst + tok) = pk;
            }
        }
    }
}

// ---------- attention: R8-original; per (b,h,half-128-rows); waves independent ----------
__global__ __launch_bounds__(256) void attn_kernel(
    const ushort_t* __restrict__ qkvb, const float* __restrict__ rpb,
    ushort_t* __restrict__ aout)
{
    __shared__ ushort_t Ps[4][32][40];          // wave-private P repack buffer
    __shared__ ushort_t Os[4][16 * 72];         // wave-private O store-repack buffer
    int t = threadIdx.x, lane = t & 63, w = t >> 6;
    int bid = blockIdx.x;                       // B*H*2 = 4096
    int qh = bid & 1; int bh = bid >> 1; int hh = bh & 7; int bg = bh >> 3;
    const ushort_t* Qg  = qkvb + (((size_t)bg * 8 + hh) * 256) * 64;
    const ushort_t* Kg  = qkvb + (((size_t)(256 + bg) * 8 + hh) * 256) * 64;
    const ushort_t* VTg = qkvb + (((size_t)(512 + bg) * 8 + hh) * 64) * 256;  // [64][256]
    int lr = lane & 15, lk = lane >> 4;
    int qrow0 = qh * 128 + w * 32;

    bf16x8 qf[2][2];
#pragma unroll
    for (int fr = 0; fr < 2; fr++)
#pragma unroll
        for (int kc = 0; kc < 2; kc++)
            qf[fr][kc] = *reinterpret_cast<const bf16x8*>(
                Qg + (size_t)(qrow0 + fr * 16 + lr) * 64 + kc * 32 + lk * 8);

    f32x4 oacc[2][4];
    float rsum[2][4];
#pragma unroll
    for (int fr = 0; fr < 2; fr++) {
#pragma unroll
        for (int fc = 0; fc < 4; fc++) oacc[fr][fc] = (f32x4){0.f, 0.f, 0.f, 0.f};
#pragma unroll
        for (int r = 0; r < 4; r++) rsum[fr][r] = 0.f;
    }

    for (int kt = 0; kt < 8; ++kt) {
        f32x4 sacc[2][2];
#pragma unroll
        for (int fr = 0; fr < 2; fr++)
#pragma unroll
            for (int fc = 0; fc < 2; fc++) sacc[fr][fc] = (f32x4){0.f, 0.f, 0.f, 0.f};
#pragma unroll
        for (int kc = 0; kc < 2; kc++) {
            bf16x8 kb0 = *reinterpret_cast<const bf16x8*>(
                Kg + (size_t)(kt * 32 + lr) * 64 + kc * 32 + lk * 8);
            bf16x8 kb1 = *reinterpret_cast<const bf16x8*>(
                Kg + (size_t)(kt * 32 + 16 + lr) * 64 + kc * 32 + lk * 8);
            sacc[0][0] = MFMA16(qf[0][kc], kb0, sacc[0][0]);
            sacc[0][1] = MFMA16(qf[0][kc], kb1, sacc[0][1]);
            sacc[1][0] = MFMA16(qf[1][kc], kb0, sacc[1][0]);
            sacc[1][1] = MFMA16(qf[1][kc], kb1, sacc[1][1]);
        }
        // bias + exp + pack P (no max-subtract: logits bounded ~|2|)
#pragma unroll
        for (int fr = 0; fr < 2; fr++)
#pragma unroll
            for (int fc = 0; fc < 2; fc++)
#pragma unroll
                for (int r = 0; r < 4; r++) {
                    int row = qrow0 + fr * 16 + lk * 4 + r;
                    int col = kt * 32 + fc * 16 + lr;
                    float lg = sacc[fr][fc][r] + rpb[((size_t)hh * 256 + row) * 256 + col];
                    float p = __expf(lg);
                    rsum[fr][r] += p;
                    Ps[w][fr * 16 + lk * 4 + r][fc * 16 + lr] = f2bf(p);
                }
        // PV
        bf16x8 pa[2], vb[4];
#pragma unroll
        for (int fr = 0; fr < 2; fr++)
            pa[fr] = *reinterpret_cast<const bf16x8*>(&Ps[w][fr * 16 + lr][lk * 8]);
#pragma unroll
        for (int fc = 0; fc < 4; fc++)
            vb[fc] = *reinterpret_cast<const bf16x8*>(
                VTg + (size_t)(fc * 16 + lr) * 256 + kt * 32 + lk * 8);
#pragma unroll
        for (int fr = 0; fr < 2; fr++)
#pragma unroll
            for (int fc = 0; fc < 4; fc++)
                oacc[fr][fc] = MFMA16(pa[fr], vb[fc], oacc[fr][fc]);
    }
    // reduce rowsum over lanes 0..15 (lr bits), reciprocal
    float rinv[2][4];
#pragma unroll
    for (int fr = 0; fr < 2; fr++)
#pragma unroll
        for (int r = 0; r < 4; r++) {
            float s = rsum[fr][r];
            s += __shfl_xor(s, 1); s += __shfl_xor(s, 2);
            s += __shfl_xor(s, 4); s += __shfl_xor(s, 8);
            rinv[fr][r] = __frcp_rn(s);
        }
    // O store via wave-private LDS repack -> 128B-contiguous per-token stores
#pragma unroll
    for (int fr = 0; fr < 2; fr++) {
#pragma unroll
        for (int fc = 0; fc < 4; fc++)
#pragma unroll
            for (int r = 0; r < 4; r++)
                Os[w][(lk * 4 + r) * 72 + fc * 16 + lr] = f2bf(oacc[fr][fc][r] * rinv[fr][r]);
#pragma unroll
        for (int ii = 0; ii < 2; ii++) {
            int j = lane + ii * 64;             // 128 chunks: 16 rows x 8 x 16B
            int row = j >> 3, ch = j & 7;
            uint4 v = *reinterpret_cast<const uint4*>(&Os[w][row * 72 + ch * 8]);
            *reinterpret_cast<uint4*>(
                aout + ((size_t)(bg * 256 + qrow0 + fr * 16 + row)) * 512 + hh * 64 + ch * 8) = v;
        }
    }
}

// ---------- proj GEMM: same 256x256/BK=64/8-wave template, fp32 out (round-8) ----------
__global__ __launch_bounds__(512, 1) void proj_gemm(
    const ushort_t* __restrict__ ain, const ushort_t* __restrict__ wT,
    const float* __restrict__ proj_b, float* __restrict__ out)
{
    __shared__ ushort_t As[2][256 * 64];
    __shared__ ushort_t Bs[2][256 * 64];
    int t = threadIdx.x;
    int bid = blockIdx.x;
    int wgid = (bid & 7) * 64 + (bid >> 3);     // 512 wgs, 64/XCD
    int mt = wgid / 2, nt = wgid % 2;
    int m0 = mt * 256, n0 = nt * 256;
    int lane = t & 63, w = t >> 6;
    int wm = w >> 2, wn = w & 3;
    int lr = lane & 15, lk = lane >> 4;
    int srow8 = lane >> 3;
    int sch = ((lane & 7) ^ srow8) * 8;
    const ushort_t* Asrc = ain + (size_t)(m0 + srow8) * 512 + sch;
    const ushort_t* Bsrc = wT + (size_t)(n0 + srow8) * 512 + sch;
    int arw = w & 3;
    int ch0 = ((lk) ^ (lr & 7)) * 8;
    int ch1 = ((4 + lk) ^ (lr & 7)) * 8;
    int arow = wm * 128 + lr;
    int brow = wn * 64 + lr;

    f32x4 acc[8][4];
#pragma unroll
    for (int fr = 0; fr < 8; fr++)
#pragma unroll
        for (int fc = 0; fc < 4; fc++) acc[fr][fc] = (f32x4){0.f, 0.f, 0.f, 0.f};

#define PSTAGE(buf, kt) do { \
    if (w < 4) { \
        _Pragma("unroll") \
        for (int i_ = 0; i_ < 8; i_++) { \
            int rb_ = arw * 64 + i_ * 8; \
            GLOAD16(Asrc + (size_t)rb_ * 512 + (kt) * 64, &As[buf][rb_ * 64]); \
        } \
    } else { \
        _Pragma("unroll") \
        for (int i_ = 0; i_ < 8; i_++) { \
            int rb_ = arw * 64 + i_ * 8; \
            GLOAD16(Bsrc + (size_t)rb_ * 512 + (kt) * 64, &Bs[buf][rb_ * 64]); \
        } \
    } } while (0)

    PSTAGE(0, 0);
    asm volatile("s_waitcnt vmcnt(0)" ::: "memory");
    __syncthreads();
    for (int kt = 0; kt < 8; ++kt) {
        int cb = kt & 1;
        if (kt < 7) PSTAGE(cb ^ 1, kt + 1);
#pragma unroll
        for (int kh = 0; kh < 2; kh++) {
            int ch = kh ? ch1 : ch0;
            bf16x8 a[8], b[4];
#pragma unroll
            for (int fr = 0; fr < 8; fr++)
                a[fr] = *reinterpret_cast<const bf16x8*>(&As[cb][(arow + fr * 16) * 64 + ch]);
#pragma unroll
            for (int fc = 0; fc < 4; fc++)
                b[fc] = *reinterpret_cast<const bf16x8*>(&Bs[cb][(brow + fc * 16) * 64 + ch]);
#pragma unroll
            for (int fr = 0; fr < 8; fr++)
#pragma unroll
                for (int fc = 0; fc < 4; fc++)
                    acc[fr][fc] = MFMA16(a[fr], b[fc], acc[fr][fc]);
        }
        if (kt < 7) {
            asm volatile("s_waitcnt vmcnt(0)" ::: "memory");
            __syncthreads();
        }
    }
#undef PSTAGE
#pragma unroll
    for (int fc = 0; fc < 4; fc++) {
        int n = n0 + wn * 64 + fc * 16 + lr;
        float bias = proj_b[n];
#pragma unroll
        for (int fr = 0; fr < 8; fr++)
#pragma unroll
            for (int r = 0; r < 4; r++) {
                int m = m0 + wm * 128 + fr * 16 + lk * 4 + r;
                out[(size_t)m * 512 + n] = acc[fr][fc][r] + bias;
            }
    }
}

extern "C" void kernel_launch(void* const* d_in, const int* in_sizes, int n_in,
                              void* d_out, int out_size, void* d_ws, size_t ws_size,
                              hipStream_t stream) {
    const float* x      = (const float*)d_in[0];
    const float* qkv_w  = (const float*)d_in[1];
    const float* qkv_b  = (const float*)d_in[2];
    const float* proj_w = (const float*)d_in[3];
    const float* proj_b = (const float*)d_in[4];
    const float* p1_w = (const float*)d_in[5];
    const float* p1_b = (const float*)d_in[6];
    const float* g1   = (const float*)d_in[7];
    const float* b1   = (const float*)d_in[8];
    const float* p2_w = (const float*)d_in[9];
    const float* p2_b = (const float*)d_in[10];
    const float* g2   = (const float*)d_in[11];
    const float* b2   = (const float*)d_in[12];
    const float* p3_w = (const float*)d_in[13];
    const float* p3_b = (const float*)d_in[14];
    const float* g3   = (const float*)d_in[15];
    const float* b3   = (const float*)d_in[16];
    const float* p4_w = (const float*)d_in[17];
    const float* p4_b = (const float*)d_in[18];
    const float* biases  = (const float*)d_in[19];
    const int*   rel_idx = (const int*)d_in[20];
    float* out = (float*)d_out;

    char* ws = (char*)d_ws;
    float*    pos    = (float*)(ws + POS_OFF);
    float*    rpb    = (float*)(ws + RPB_OFF);
    ushort_t* wqkvT  = (ushort_t*)(ws + WQKV_OFF);
    ushort_t* wprojT = (ushort_t*)(ws + WPROJ_OFF);
    ushort_t* qkvb   = (ushort_t*)(ws + QKV_OFF);
    ushort_t* aoutb  = (ushort_t*)(ws + AOUT_OFF);
    ushort_t* xb     = (ushort_t*)(ws + XB_OFF);     // overlays aoutb (disjoint lifetime)

    prologue<<<dim3(PRO_TOTAL), dim3(256), 0, stream>>>(
        x, xb, qkv_w, wqkvT, proj_w, wprojT, biases,
        p1_w, p1_b, g1, b1, p2_w, p2_b, g2, b2,
        p3_w, p3_b, g3, b3, p4_w, p4_b, pos);
    rpb_gather<<<dim3(256), dim3(256), 0, stream>>>(pos, rel_idx, rpb);
    qkv_gemm<<<dim3(1536), dim3(512), 0, stream>>>(xb, wqkvT, qkv_b, qkvb);
    attn_kernel<<<dim3(4096), dim3(256), 0, stream>>>(qkvb, rpb, aoutb);
    proj_gemm<<<dim3(512), dim3(512), 0, stream>>>(aoutb, wprojT, proj_b, out);
}

// Round 14
// 366.631 us; speedup vs baseline: 1.1682x; 1.0084x over previous
//
#include <hip/hip_runtime.h>
#include <stdint.h>

typedef __bf16 bf16x8 __attribute__((ext_vector_type(8)));
typedef float  f32x4  __attribute__((ext_vector_type(4)));
typedef unsigned short ushort_t;

#define MFMA16(a,b,c) __builtin_amdgcn_mfma_f32_16x16x32_bf16((a),(b),(c),0,0,0)

// async global->LDS, 16B per lane; LDS dest must be wave-uniform base (HW adds lane*16)
#define GLOAD16(gsrc, ldst) \
    __builtin_amdgcn_global_load_lds((const __attribute__((address_space(1))) void*)(gsrc), \
                                     (__attribute__((address_space(3))) void*)(ldst), 16, 0, 0)

// ---------- constants ----------
#define BATCH 256
#define NTOK  256
#define DIM   512
#define NH    8
#define HD    64
#define PD    32
#define LTAB  961

// workspace layout (bytes)
#define POS_OFF   0                         // 961*8*4
#define RPB_OFF   32768                     // 8*256*256*4 = 2 MB
#define WQKV_OFF  (RPB_OFF + 2097152)       // 1536*512*2
#define WPROJ_OFF (WQKV_OFF + 1572864)      // 512*512*2
#define QKV_OFF   (WPROJ_OFF + 524288)      // 3*256*8*256*64*2 = 192 MB
#define AOUT_OFF  (QKV_OFF + 201326592)     // 65536*512*2 = 64 MB
#define XB_OFF    AOUT_OFF                  // xb overlays aout: disjoint lifetimes

__device__ __forceinline__ ushort_t f2bf(float f) {
    unsigned int u = __builtin_bit_cast(unsigned int, f);
    u += 0x7FFFu + ((u >> 16) & 1u);
    return (ushort_t)(u >> 16);
}

// ---------- fused prologue: convert_x | transpose_w(qkv) | transpose_w(proj) | pos_mlp ----------
#define PRO_CONV  16384
#define PRO_TQKV  (PRO_CONV + 192)
#define PRO_TPROJ (PRO_TQKV + 64)
#define PRO_TOTAL (PRO_TPROJ + 121)

__device__ __forceinline__ void transpose_body(
    const float* __restrict__ src, ushort_t* __restrict__ dst,
    int K, int Nn, int bid, int t, ushort_t (*tile)[65])
{
    int tiles_n = Nn >> 6;
    int tn = bid % tiles_n, tk = bid / tiles_n;
    int n0 = tn * 64, k0 = tk * 64;
#pragma unroll
    for (int i = 0; i < 16; i++) {
        int idx = t + i * 256;
        int kl = idx >> 6, nl = idx & 63;
        tile[nl][kl] = f2bf(src[(size_t)(k0 + kl) * Nn + n0 + nl]);
    }
    __syncthreads();
#pragma unroll
    for (int i = 0; i < 16; i++) {
        int idx = t + i * 256;
        int nl = idx >> 6, kl = idx & 63;
        dst[(size_t)(n0 + nl) * K + k0 + kl] = tile[nl][kl];
    }
}

__device__ __forceinline__ float ln_relu_t(float h, int j,
                                           const float* __restrict__ g,
                                           const float* __restrict__ bb) {
    float m = h;
    m += __shfl_xor(m, 1); m += __shfl_xor(m, 2); m += __shfl_xor(m, 4);
    m += __shfl_xor(m, 8); m += __shfl_xor(m, 16);
    m *= (1.0f / PD);
    float d = h - m;
    float v = d * d;
    v += __shfl_xor(v, 1); v += __shfl_xor(v, 2); v += __shfl_xor(v, 4);
    v += __shfl_xor(v, 8); v += __shfl_xor(v, 16);
    v *= (1.0f / PD);
    float x = d * rsqrtf(v + 1e-5f) * g[j] + bb[j];
    return x > 0.f ? x : 0.f;
}

__global__ __launch_bounds__(256) void prologue(
    const float* __restrict__ x, ushort_t* __restrict__ xb,
    const float* __restrict__ qkv_w, ushort_t* __restrict__ wqkvT,
    const float* __restrict__ proj_w, ushort_t* __restrict__ wprojT,
    const float* __restrict__ biases,
    const float* __restrict__ p1_w, const float* __restrict__ p1_b,
    const float* __restrict__ g1, const float* __restrict__ b1,
    const float* __restrict__ p2_w, const float* __restrict__ p2_b,
    const float* __restrict__ g2, const float* __restrict__ b2,
    const float* __restrict__ p3_w, const float* __restrict__ p3_b,
    const float* __restrict__ g3, const float* __restrict__ b3,
    const float* __restrict__ p4_w, const float* __restrict__ p4_b,
    float* __restrict__ pos)
{
    __shared__ ushort_t tile[64][65];
    __shared__ float hs[8][33];
    int b = blockIdx.x, tid = threadIdx.x;
    if (b < PRO_CONV) {
        size_t i = ((size_t)b * 256 + tid) * 8;
        float4 f0 = *(const float4*)(x + i);
        float4 f1 = *(const float4*)(x + i + 4);
        uint4 o;
        o.x = (unsigned)f2bf(f0.x) | ((unsigned)f2bf(f0.y) << 16);
        o.y = (unsigned)f2bf(f0.z) | ((unsigned)f2bf(f0.w) << 16);
        o.z = (unsigned)f2bf(f1.x) | ((unsigned)f2bf(f1.y) << 16);
        o.w = (unsigned)f2bf(f1.z) | ((unsigned)f2bf(f1.w) << 16);
        *reinterpret_cast<uint4*>(xb + i) = o;
    } else if (b < PRO_TQKV) {
        transpose_body(qkv_w, wqkvT, 512, 1536, b - PRO_CONV, tid, tile);
    } else if (b < PRO_TPROJ) {
        transpose_body(proj_w, wprojT, 512, 512, b - PRO_TQKV, tid, tile);
    } else {
        int rl = tid >> 5, j = tid & 31;
        int r = (b - PRO_TPROJ) * 8 + rl;
        bool ok = r < LTAB;
        float c0 = ok ? biases[r * 2 + 0] : 0.f;
        float c1 = ok ? biases[r * 2 + 1] : 0.f;

        float h = c0 * p1_w[j] + c1 * p1_w[PD + j] + p1_b[j];
        h = ln_relu_t(h, j, g1, b1);

        hs[rl][j] = h;
        __syncthreads();
        float s = p2_b[j];
#pragma unroll
        for (int i = 0; i < PD; i++) s += hs[rl][i] * p2_w[i * PD + j];
        __syncthreads();
        h = ln_relu_t(s, j, g2, b2);

        hs[rl][j] = h;
        __syncthreads();
        s = p3_b[j];
#pragma unroll
        for (int i = 0; i < PD; i++) s += hs[rl][i] * p3_w[i * PD + j];
        __syncthreads();
        h = ln_relu_t(s, j, g3, b3);

        hs[rl][j] = h;
        __syncthreads();
        if (ok && j < NH) {
            float o = p4_b[j];
#pragma unroll
            for (int i = 0; i < PD; i++) o += hs[rl][i] * p4_w[i * NH + j];
            pos[r * NH + j] = o;
        }
    }
}

// ---------- rpb gather ----------
__global__ __launch_bounds__(256) void rpb_gather(
    const float* __restrict__ pos, const int* __restrict__ rel_idx,
    float* __restrict__ rpb)
{
    int i = blockIdx.x * 256 + threadIdx.x;   // < 65536
    int idx = rel_idx[i];
#pragma unroll
    for (int hh = 0; hh < NH; hh++) rpb[(size_t)hh * 65536 + i] = pos[idx * NH + hh];
}

// ---------- QKV GEMM: 256x256, BK=64, 8 waves; counted vmcnt + RAW barriers (T4) ----------
// Per iter: STAGE(t+1); vmcnt(8) [t's loads landed, t+1's 8 stay in flight];
// raw s_barrier; ds_read+MFMA(t); raw s_barrier. __syncthreads is NOT used in the
// loop because it drains vmcnt(0) before s_barrier, which defeats counted waits.
__global__ __launch_bounds__(512, 1) void qkv_gemm(
    const ushort_t* __restrict__ xb, const ushort_t* __restrict__ wT,
    const float* __restrict__ qkv_b, ushort_t* __restrict__ qkvb)
{
    __shared__ ushort_t As[2][256 * 64];   // 32 KB each buf
    __shared__ ushort_t Bs[2][256 * 64];
    int t = threadIdx.x;
    int bid = blockIdx.x;
    int wgid = (bid & 7) * 192 + (bid >> 3);    // 1536 wgs, 192/XCD
    int mt = wgid / 6, nt = wgid % 6;           // n fastest within XCD chunk
    int m0 = mt * 256, n0 = nt * 256;
    int lane = t & 63, w = t >> 6;              // 8 waves
    int wm = w >> 2, wn = w & 3;                // 2M x 4N wave grid, wave out 128x64
    int lr = lane & 15, lk = lane >> 4;
    int srow8 = lane >> 3;
    int sch = ((lane & 7) ^ srow8) * 8;         // pre-swizzled source chunk
    const ushort_t* Asrc = xb + (size_t)(m0 + srow8) * 512 + sch;
    const ushort_t* Bsrc = wT + (size_t)(n0 + srow8) * 512 + sch;
    int arw = w & 3;
    int ch0 = ((lk) ^ (lr & 7)) * 8;
    int ch1 = ((4 + lk) ^ (lr & 7)) * 8;
    int arow = wm * 128 + lr;
    int brow = wn * 64 + lr;

    f32x4 acc[8][4];
#pragma unroll
    for (int fr = 0; fr < 8; fr++)
#pragma unroll
        for (int fc = 0; fc < 4; fc++) acc[fr][fc] = (f32x4){0.f, 0.f, 0.f, 0.f};

#define QSTAGE(buf, kt) do { \
    if (w < 4) { \
        _Pragma("unroll") \
        for (int i_ = 0; i_ < 8; i_++) { \
            int rb_ = arw * 64 + i_ * 8; \
            GLOAD16(Asrc + (size_t)rb_ * 512 + (kt) * 64, &As[buf][rb_ * 64]); \
        } \
    } else { \
        _Pragma("unroll") \
        for (int i_ = 0; i_ < 8; i_++) { \
            int rb_ = arw * 64 + i_ * 8; \
            GLOAD16(Bsrc + (size_t)rb_ * 512 + (kt) * 64, &Bs[buf][rb_ * 64]); \
        } \
    } } while (0)

    QSTAGE(0, 0);
    asm volatile("s_waitcnt vmcnt(0)" ::: "memory");
    __builtin_amdgcn_s_barrier();
    for (int kt = 0; kt < 8; ++kt) {
        int cb = kt & 1;
        if (kt < 7) QSTAGE(cb ^ 1, kt + 1);     // 8 loads into the other buffer
        if (kt > 0) {
            // own stage(kt) loads landed; stage(kt+1)'s 8 remain in flight
            if (kt < 7) asm volatile("s_waitcnt vmcnt(8)" ::: "memory");
            else        asm volatile("s_waitcnt vmcnt(0)" ::: "memory");
            __builtin_amdgcn_sched_barrier(0);
            __builtin_amdgcn_s_barrier();       // all waves landed stage(kt)
        }
#pragma unroll
        for (int kh = 0; kh < 2; kh++) {
            int ch = kh ? ch1 : ch0;
            bf16x8 a[8], b[4];
#pragma unroll
            for (int fr = 0; fr < 8; fr++)
                a[fr] = *reinterpret_cast<const bf16x8*>(&As[cb][(arow + fr * 16) * 64 + ch]);
#pragma unroll
            for (int fc = 0; fc < 4; fc++)
                b[fc] = *reinterpret_cast<const bf16x8*>(&Bs[cb][(brow + fc * 16) * 64 + ch]);
#pragma unroll
            for (int fr = 0; fr < 8; fr++)
#pragma unroll
                for (int fc = 0; fc < 4; fc++)
                    acc[fr][fc] = MFMA16(a[fr], b[fc], acc[fr][fc]);
        }
        if (kt < 7) {
            // all waves done ds_reading buf cb before next iter's STAGE overwrites it
            // (lgkm for these reads already drained by MFMA data deps)
            __builtin_amdgcn_s_barrier();
        }
    }
#undef QSTAGE

    // epilogue: s = q/k/v uniform per block; bg uniform (m0 mult of 256)
    int s = n0 >> 9;
    int bg = m0 >> 8;
    if (s < 2) {
        float sc = (s == 0) ? 0.125f : 1.0f;
#pragma unroll
        for (int fc = 0; fc < 4; fc++) {
            int n = n0 + wn * 64 + fc * 16 + lr;
            float bias = qkv_b[n];
            int hh = (n >> 6) & 7, d = n & 63;
            ushort_t* dst = qkvb + ((((size_t)s * 256 + bg) * 8 + hh) * 256) * 64 + d;
#pragma unroll
            for (int fr = 0; fr < 8; fr++)
#pragma unroll
                for (int r = 0; r < 4; r++) {
                    int tok = wm * 128 + fr * 16 + lk * 4 + r;
                    dst[(size_t)tok * 64] = f2bf((acc[fr][fc][r] + bias) * sc);
                }
        }
    } else {
        // V transposed [B,H,64,N]: pack 4 contiguous tokens -> one 8B store
#pragma unroll
        for (int fc = 0; fc < 4; fc++) {
            int n = n0 + wn * 64 + fc * 16 + lr;
            float bias = qkv_b[n];
            int hh = (n >> 6) & 7, d = n & 63;
            ushort_t* dst = qkvb + ((((size_t)512 + bg) * 8 + hh) * 64 + d) * 256;
#pragma unroll
            for (int fr = 0; fr < 8; fr++) {
                int tok = wm * 128 + fr * 16 + lk * 4;
                uint2 pk;
                pk.x = (unsigned)f2bf(acc[fr][fc][0] + bias) |
                       ((unsigned)f2bf(acc[fr][fc][1] + bias) << 16);
                pk.y = (unsigned)f2bf(acc[fr][fc][2] + bias) |
                       ((unsigned)f2bf(acc[fr][fc][3] + bias) << 16);
                *reinterpret_cast<uint2*>(dst + tok) = pk;
            }
        }
    }
}

// ---------- attention: R8-original; per (b,h,half-128-rows); waves independent ----------
__global__ __launch_bounds__(256) void attn_kernel(
    const ushort_t* __restrict__ qkvb, const float* __restrict__ rpb,
    ushort_t* __restrict__ aout)
{
    __shared__ ushort_t Ps[4][32][40];          // wave-private P repack buffer
    __shared__ ushort_t Os[4][16 * 72];         // wave-private O store-repack buffer
    int t = threadIdx.x, lane = t & 63, w = t >> 6;
    int bid = blockIdx.x;                       // B*H*2 = 4096
    int qh = bid & 1; int bh = bid >> 1; int hh = bh & 7; int bg = bh >> 3;
    const ushort_t* Qg  = qkvb + (((size_t)bg * 8 + hh) * 256) * 64;
    const ushort_t* Kg  = qkvb + (((size_t)(256 + bg) * 8 + hh) * 256) * 64;
    const ushort_t* VTg = qkvb + (((size_t)(512 + bg) * 8 + hh) * 64) * 256;  // [64][256]
    int lr = lane & 15, lk = lane >> 4;
    int qrow0 = qh * 128 + w * 32;

    bf16x8 qf[2][2];
#pragma unroll
    for (int fr = 0; fr < 2; fr++)
#pragma unroll
        for (int kc = 0; kc < 2; kc++)
            qf[fr][kc] = *reinterpret_cast<const bf16x8*>(
                Qg + (size_t)(qrow0 + fr * 16 + lr) * 64 + kc * 32 + lk * 8);

    f32x4 oacc[2][4];
    float rsum[2][4];
#pragma unroll
    for (int fr = 0; fr < 2; fr++) {
#pragma unroll
        for (int fc = 0; fc < 4; fc++) oacc[fr][fc] = (f32x4){0.f, 0.f, 0.f, 0.f};
#pragma unroll
        for (int r = 0; r < 4; r++) rsum[fr][r] = 0.f;
    }

    for (int kt = 0; kt < 8; ++kt) {
        f32x4 sacc[2][2];
#pragma unroll
        for (int fr = 0; fr < 2; fr++)
#pragma unroll
            for (int fc = 0; fc < 2; fc++) sacc[fr][fc] = (f32x4){0.f, 0.f, 0.f, 0.f};
#pragma unroll
        for (int kc = 0; kc < 2; kc++) {
            bf16x8 kb0 = *reinterpret_cast<const bf16x8*>(
                Kg + (size_t)(kt * 32 + lr) * 64 + kc * 32 + lk * 8);
            bf16x8 kb1 = *reinterpret_cast<const bf16x8*>(
                Kg + (size_t)(kt * 32 + 16 + lr) * 64 + kc * 32 + lk * 8);
            sacc[0][0] = MFMA16(qf[0][kc], kb0, sacc[0][0]);
            sacc[0][1] = MFMA16(qf[0][kc], kb1, sacc[0][1]);
            sacc[1][0] = MFMA16(qf[1][kc], kb0, sacc[1][0]);
            sacc[1][1] = MFMA16(qf[1][kc], kb1, sacc[1][1]);
        }
        // bias + exp + pack P (no max-subtract: logits bounded ~|2|)
#pragma unroll
        for (int fr = 0; fr < 2; fr++)
#pragma unroll
            for (int fc = 0; fc < 2; fc++)
#pragma unroll
                for (int r = 0; r < 4; r++) {
                    int row = qrow0 + fr * 16 + lk * 4 + r;
                    int col = kt * 32 + fc * 16 + lr;
                    float lg = sacc[fr][fc][r] + rpb[((size_t)hh * 256 + row) * 256 + col];
                    float p = __expf(lg);
                    rsum[fr][r] += p;
                    Ps[w][fr * 16 + lk * 4 + r][fc * 16 + lr] = f2bf(p);
                }
        // PV
        bf16x8 pa[2], vb[4];
#pragma unroll
        for (int fr = 0; fr < 2; fr++)
            pa[fr] = *reinterpret_cast<const bf16x8*>(&Ps[w][fr * 16 + lr][lk * 8]);
#pragma unroll
        for (int fc = 0; fc < 4; fc++)
            vb[fc] = *reinterpret_cast<const bf16x8*>(
                VTg + (size_t)(fc * 16 + lr) * 256 + kt * 32 + lk * 8);
#pragma unroll
        for (int fr = 0; fr < 2; fr++)
#pragma unroll
            for (int fc = 0; fc < 4; fc++)
                oacc[fr][fc] = MFMA16(pa[fr], vb[fc], oacc[fr][fc]);
    }
    // reduce rowsum over lanes 0..15 (lr bits), reciprocal
    float rinv[2][4];
#pragma unroll
    for (int fr = 0; fr < 2; fr++)
#pragma unroll
        for (int r = 0; r < 4; r++) {
            float s = rsum[fr][r];
            s += __shfl_xor(s, 1); s += __shfl_xor(s, 2);
            s += __shfl_xor(s, 4); s += __shfl_xor(s, 8);
            rinv[fr][r] = __frcp_rn(s);
        }
    // O store via wave-private LDS repack -> 128B-contiguous per-token stores
#pragma unroll
    for (int fr = 0; fr < 2; fr++) {
#pragma unroll
        for (int fc = 0; fc < 4; fc++)
#pragma unroll
            for (int r = 0; r < 4; r++)
                Os[w][(lk * 4 + r) * 72 + fc * 16 + lr] = f2bf(oacc[fr][fc][r] * rinv[fr][r]);
#pragma unroll
        for (int ii = 0; ii < 2; ii++) {
            int j = lane + ii * 64;             // 128 chunks: 16 rows x 8 x 16B
            int row = j >> 3, ch = j & 7;
            uint4 v = *reinterpret_cast<const uint4*>(&Os[w][row * 72 + ch * 8]);
            *reinterpret_cast<uint4*>(
                aout + ((size_t)(bg * 256 + qrow0 + fr * 16 + row)) * 512 + hh * 64 + ch * 8) = v;
        }
    }
}

// ---------- proj GEMM: same template with counted vmcnt + RAW barriers, fp32 out ----------
__global__ __launch_bounds__(512, 1) void proj_gemm(
    const ushort_t* __restrict__ ain, const ushort_t* __restrict__ wT,
    const float* __restrict__ proj_b, float* __restrict__ out)
{
    __shared__ ushort_t As[2][256 * 64];
    __shared__ ushort_t Bs[2][256 * 64];
    int t = threadIdx.x;
    int bid = blockIdx.x;
    int wgid = (bid & 7) * 64 + (bid >> 3);     // 512 wgs, 64/XCD
    int mt = wgid / 2, nt = wgid % 2;
    int m0 = mt * 256, n0 = nt * 256;
    int lane = t & 63, w = t >> 6;
    int wm = w >> 2, wn = w & 3;
    int lr = lane & 15, lk = lane >> 4;
    int srow8 = lane >> 3;
    int sch = ((lane & 7) ^ srow8) * 8;
    const ushort_t* Asrc = ain + (size_t)(m0 + srow8) * 512 + sch;
    const ushort_t* Bsrc = wT + (size_t)(n0 + srow8) * 512 + sch;
    int arw = w & 3;
    int ch0 = ((lk) ^ (lr & 7)) * 8;
    int ch1 = ((4 + lk) ^ (lr & 7)) * 8;
    int arow = wm * 128 + lr;
    int brow = wn * 64 + lr;

    f32x4 acc[8][4];
#pragma unroll
    for (int fr = 0; fr < 8; fr++)
#pragma unroll
        for (int fc = 0; fc < 4; fc++) acc[fr][fc] = (f32x4){0.f, 0.f, 0.f, 0.f};

#define PSTAGE(buf, kt) do { \
    if (w < 4) { \
        _Pragma("unroll") \
        for (int i_ = 0; i_ < 8; i_++) { \
            int rb_ = arw * 64 + i_ * 8; \
            GLOAD16(Asrc + (size_t)rb_ * 512 + (kt) * 64, &As[buf][rb_ * 64]); \
        } \
    } else { \
        _Pragma("unroll") \
        for (int i_ = 0; i_ < 8; i_++) { \
            int rb_ = arw * 64 + i_ * 8; \
            GLOAD16(Bsrc + (size_t)rb_ * 512 + (kt) * 64, &Bs[buf][rb_ * 64]); \
        } \
    } } while (0)

    PSTAGE(0, 0);
    asm volatile("s_waitcnt vmcnt(0)" ::: "memory");
    __builtin_amdgcn_s_barrier();
    for (int kt = 0; kt < 8; ++kt) {
        int cb = kt & 1;
        if (kt < 7) PSTAGE(cb ^ 1, kt + 1);
        if (kt > 0) {
            if (kt < 7) asm volatile("s_waitcnt vmcnt(8)" ::: "memory");
            else        asm volatile("s_waitcnt vmcnt(0)" ::: "memory");
            __builtin_amdgcn_sched_barrier(0);
            __builtin_amdgcn_s_barrier();
        }
#pragma unroll
        for (int kh = 0; kh < 2; kh++) {
            int ch = kh ? ch1 : ch0;
            bf16x8 a[8], b[4];
#pragma unroll
            for (int fr = 0; fr < 8; fr++)
                a[fr] = *reinterpret_cast<const bf16x8*>(&As[cb][(arow + fr * 16) * 64 + ch]);
#pragma unroll
            for (int fc = 0; fc < 4; fc++)
                b[fc] = *reinterpret_cast<const bf16x8*>(&Bs[cb][(brow + fc * 16) * 64 + ch]);
#pragma unroll
            for (int fr = 0; fr < 8; fr++)
#pragma unroll
                for (int fc = 0; fc < 4; fc++)
                    acc[fr][fc] = MFMA16(a[fr], b[fc], acc[fr][fc]);
        }
        if (kt < 7) {
            __builtin_amdgcn_s_barrier();
        }
    }
#undef PSTAGE
#pragma unroll
    for (int fc = 0; fc < 4; fc++) {
        int n = n0 + wn * 64 + fc * 16 + lr;
        float bias = proj_b[n];
#pragma unroll
        for (int fr = 0; fr < 8; fr++)
#pragma unroll
            for (int r = 0; r < 4; r++) {
                int m = m0 + wm * 128 + fr * 16 + lk * 4 + r;
                out[(size_t)m * 512 + n] = acc[fr][fc][r] + bias;
            }
    }
}

extern "C" void kernel_launch(void* const* d_in, const int* in_sizes, int n_in,
                              void* d_out, int out_size, void* d_ws, size_t ws_size,
                              hipStream_t stream) {
    const float* x      = (const float*)d_in[0];
    const float* qkv_w  = (const float*)d_in[1];
    const float* qkv_b  = (const float*)d_in[2];
    const float* proj_w = (const float*)d_in[3];
    const float* proj_b = (const float*)d_in[4];
    const float* p1_w = (const float*)d_in[5];
    const float* p1_b = (const float*)d_in[6];
    const float* g1   = (const float*)d_in[7];
    const float* b1   = (const float*)d_in[8];
    const float* p2_w = (const float*)d_in[9];
    const float* p2_b = (const float*)d_in[10];
    const float* g2   = (const float*)d_in[11];
    const float* b2   = (const float*)d_in[12];
    const float* p3_w = (const float*)d_in[13];
    const float* p3_b = (const float*)d_in[14];
    const float* g3   = (const float*)d_in[15];
    const float* b3   = (const float*)d_in[16];
    const float* p4_w = (const float*)d_in[17];
    const float* p4_b = (const float*)d_in[18];
    const float* biases  = (const float*)d_in[19];
    const int*   rel_idx = (const int*)d_in[20];
    float* out = (float*)d_out;

    char* ws = (char*)d_ws;
    float*    pos    = (float*)(ws + POS_OFF);
    float*    rpb    = (float*)(ws + RPB_OFF);
    ushort_t* wqkvT  = (ushort_t*)(ws + WQKV_OFF);
    ushort_t* wprojT = (ushort_t*)(ws + WPROJ_OFF);
    ushort_t* qkvb   = (ushort_t*)(ws + QKV_OFF);
    ushort_t* aoutb  = (ushort_t*)(ws + AOUT_OFF);
    ushort_t* xb     = (ushort_t*)(ws + XB_OFF);     // overlays aoutb (disjoint lifetime)

    prologue<<<dim3(PRO_TOTAL), dim3(256), 0, stream>>>(
        x, xb, qkv_w, wqkvT, proj_w, wprojT, biases,
        p1_w, p1_b, g1, b1, p2_w, p2_b, g2, b2,
        p3_w, p3_b, g3, b3, p4_w, p4_b, pos);
    rpb_gather<<<dim3(256), dim3(256), 0, stream>>>(pos, rel_idx, rpb);
    qkv_gemm<<<dim3(1536), dim3(512), 0, stream>>>(xb, wqkvT, qkv_b, qkvb);
    attn_kernel<<<dim3(4096), dim3(256), 0, stream>>>(qkvb, rpb, aoutb);
    proj_gemm<<<dim3(512), dim3(512), 0, stream>>>(aoutb, wprojT, proj_b, out);
}